// Round 4
// baseline (1738.322 us; speedup 1.0000x reference)
//
#include <hip/hip_runtime.h>
#include <hip/hip_bf16.h>
#include <math.h>

#define HH 384
#define WW 384
#define HWSZ (HH*WW)   // 147456
#define BB 4

typedef __attribute__((ext_vector_type(8))) short short8;
typedef __attribute__((ext_vector_type(4))) float f32x4;

// ---- workspace layout (float offsets). TOTAL: 16384 + 56,623,104 + 73,728
// = 56,713,216 fl = 226.9 MB (226.6 proved OK in r2-r4).
static const size_t OFF_MISC = 0;        // 16384 floats
static const size_t OFF_A    = 16384;    // big region, 56,623,104 floats
static const size_t OFF_BW   = OFF_A + 56623104;   // 73,728 fl branch weights
// region-A sequenced reuse (float offsets within A):
//   det phase:  x0 bf16   @0          ; f1 bf16 @2,359,296 ; f2 bf16 @7,077,888
//               d3out bf16@16,515,072 (ends 35,389,440)
//               det W' bf16 @56,423,104 (ends 56,616,640)
//   branch:     xs_hi @0 (9.44M fl) ; xs_lo @9.44M ; t1_hi @18.87M ; t1_lo @37.75M
//               (t1_lo overwrites det W' - dead by then; xb lives in d_out)
//   qkv:        qkvp fp32 @0 (56,623,104 fl)
// misc (float offsets):
static const size_t MISC_POOLED = 0;     // 256 floats
static const size_t MISC_PRED   = 1024;  // 1 int
static const size_t MISC_STATS  = 1056;  // 768 floats
static const size_t MISC_MB     = 2048;  // 4096 floats

#define LPAD 40   // LDS row stride in ushorts: (cell*80+quad*16)/4 %32 covers
                  // all 32 banks 2-way (free) vs stride 32's 8-way conflict.

__device__ __forceinline__ float waveSum(float v) {
#pragma unroll
    for (int off = 32; off > 0; off >>= 1) v += __shfl_down(v, off);
    return v;
}

__device__ __forceinline__ float gelu_exact(float v) {
    return 0.5f * v * (1.0f + erff(v * 0.70710678118654752f));
}

__device__ __forceinline__ unsigned short f2bf(float f) {
    __hip_bfloat16 h = __float2bfloat16(f);
    return *(unsigned short*)&h;
}
__device__ __forceinline__ float bf2f(unsigned short u) {
    unsigned int b = ((unsigned int)u) << 16;
    return __uint_as_float(b);
}

// 3x3 depthwise conv, zero-pad, 8 consecutive pixels of row y at column xg
// (xg multiple of 8). Proven no-spill form (R1: 48 VGPR, WRITE_SIZE clean).
__device__ __forceinline__ void dwconv8(const float* __restrict__ base,
                                        const float* __restrict__ w9,
                                        int y, int xg, float o[8])
{
#pragma unroll
    for (int j = 0; j < 8; ++j) o[j] = 0.f;
#pragma unroll
    for (int dy = 0; dy < 3; ++dy) {
        int gy = y + dy - 1;
        if ((unsigned)gy >= (unsigned)HH) continue;
        const float* rp = base + (size_t)gy * WW + xg;
        f32x4 m0 = *(const f32x4*)(rp);
        f32x4 m1 = *(const f32x4*)(rp + 4);
        float r0 = (xg > 0) ? rp[-1] : 0.f;
        float r9 = (xg + 8 < WW) ? rp[8] : 0.f;
        float r[10] = {r0, m0[0], m0[1], m0[2], m0[3],
                           m1[0], m1[1], m1[2], m1[3], r9};
        float w0 = w9[dy * 3 + 0], w1 = w9[dy * 3 + 1], w2 = w9[dy * 3 + 2];
#pragma unroll
        for (int j = 0; j < 8; ++j)
            o[j] = fmaf(r[j], w0, fmaf(r[j + 1], w1, fmaf(r[j + 2], w2, o[j])));
    }
}

// --- spill-proof batched-load helpers for qkdwstats (4 px/thread) ----------
// Loads are UNCONDITIONAL (addresses clamped in-bounds; out-of-range taps
// zeroed by select AFTER the load) so the compiler can batch them freely.
// All outputs are plain arrays written at compile-time-constant indices in
// fully-unrolled code -> SROA keeps them in VGPRs.
__device__ __forceinline__ void dwload4v(const float* __restrict__ base,
                                         int y, int xg,
                                         f32x4 m[3], float e0[3], float e1[3])
{
#pragma unroll
    for (int dy = 0; dy < 3; ++dy) {
        int gy = y + dy - 1;
        int cy = gy < 0 ? 0 : (gy > HH - 1 ? HH - 1 : gy);
        const float* rp = base + (size_t)cy * WW + xg;
        f32x4 v = *(const f32x4*)rp;
        float a = rp[xg > 0 ? -1 : 0];
        float bvl = rp[xg + 4 < WW ? 4 : 3];
        bool ok = (unsigned)gy < (unsigned)HH;
        m[dy]  = ok ? v : (f32x4){0.f, 0.f, 0.f, 0.f};
        e0[dy] = (ok && xg > 0)      ? a   : 0.f;
        e1[dy] = (ok && xg + 4 < WW) ? bvl : 0.f;
    }
}

__device__ __forceinline__ void dwapply4v(const f32x4 m[3], const float e0[3],
                                          const float e1[3],
                                          const float* __restrict__ w9,
                                          float o[4])
{
#pragma unroll
    for (int j = 0; j < 4; ++j) o[j] = 0.f;
#pragma unroll
    for (int dy = 0; dy < 3; ++dy) {
        float r[6] = {e0[dy], m[dy][0], m[dy][1], m[dy][2], m[dy][3], e1[dy]};
        float w0 = w9[dy * 3 + 0], w1 = w9[dy * 3 + 1], w2 = w9[dy * 3 + 2];
#pragma unroll
        for (int j = 0; j < 4; ++j)
            o[j] = fmaf(r[j], w0, fmaf(r[j + 1], w1, fmaf(r[j + 2], w2, o[j])));
    }
}

// ===========================================================================
// DETECTOR PATH (bf16 MFMA) — only argmax(logits[0]) is consumed.
// ===========================================================================

// x batch0: NCHW fp32 -> NHWC bf16
__global__ __launch_bounds__(256) void xcvt_kernel(
    const float* __restrict__ x, unsigned short* __restrict__ x0)
{
    int px = blockIdx.x * 256 + threadIdx.x;
    if (px >= HWSZ) return;
    unsigned short u[32];
#pragma unroll
    for (int c = 0; c < 32; ++c) u[c] = f2bf(x[(size_t)c * HWSZ + px]);
    uint4* dst = (uint4*)(x0 + (size_t)px * 32);
#pragma unroll
    for (int g = 0; g < 4; ++g) {
        uint4 v;
        v.x = (unsigned)u[g*8+0] | ((unsigned)u[g*8+1] << 16);
        v.y = (unsigned)u[g*8+2] | ((unsigned)u[g*8+3] << 16);
        v.z = (unsigned)u[g*8+4] | ((unsigned)u[g*8+5] << 16);
        v.w = (unsigned)u[g*8+6] | ((unsigned)u[g*8+7] << 16);
        dst[g] = v;
    }
}

// weights OIHW fp32 -> [co][e=dy*3+dx][ci] bf16
__global__ __launch_bounds__(256) void wcvt_kernel(
    const float* __restrict__ w, unsigned short* __restrict__ wp,
    int Cin, int total)
{
    int t = blockIdx.x * 256 + threadIdx.x;
    if (t >= total) return;
    int nine_cin = 9 * Cin;
    int co = t / nine_cin;
    int r = t - co * nine_cin;
    int e = r / Cin;
    int ci = r - e * Cin;
    wp[t] = f2bf(w[(size_t)co * nine_cin + ci * 9 + e]);
}

// implicit-GEMM 3x3 conv, pad=1, bias+ReLU, NHWC bf16 (detector).
template<int CIN, int COUT>
__global__ __launch_bounds__(256) void mfma_conv2_kernel(
    const unsigned short* __restrict__ in,
    const unsigned short* __restrict__ wp,
    const float* __restrict__ bias,
    unsigned short* __restrict__ out)
{
    constexpr int NT = COUT / 64;
    __shared__ unsigned short s_in[198 * LPAD];

    const int tid  = threadIdx.x;
    const int lane = tid & 63;
    const int wave = tid >> 6;
    const int nl   = lane & 15;
    const int quad = lane >> 4;
    const int row  = blockIdx.x / 6;
    const int x0   = (blockIdx.x % 6) * 64;
    const int co_w0 = wave * (COUT / 4);

    f32x4 acc[4][NT];
#pragma unroll
    for (int pg = 0; pg < 4; ++pg)
#pragma unroll
        for (int ct = 0; ct < NT; ++ct) acc[pg][ct] = (f32x4){0.f,0.f,0.f,0.f};

#pragma unroll
    for (int ci0 = 0; ci0 < CIN; ci0 += 32) {
        __syncthreads();
        for (int idx = tid; idx < 792; idx += 256) {
            int qs   = idx & 3;
            int cell = idx >> 2;
            int px   = cell % 66;
            int r    = cell / 66;
            int gy   = row + r - 1;
            int gx   = x0 + px - 1;
            uint4 v = {0u,0u,0u,0u};
            if ((unsigned)gy < (unsigned)HH && (unsigned)gx < (unsigned)WW)
                v = *(const uint4*)(in + (size_t)(gy * WW + gx) * CIN + ci0 + qs * 8);
            *(uint4*)(s_in + cell * LPAD + qs * 8) = v;
        }
        __syncthreads();
#pragma unroll
        for (int e = 0; e < 9; ++e) {
            const int er = e / 3, ec = e % 3;
            short8 bfrag[4];
#pragma unroll
            for (int pg = 0; pg < 4; ++pg)
                bfrag[pg] = *(const short8*)(s_in + ((er * 66 + pg * 16 + nl + ec) * LPAD + quad * 8));
#pragma unroll
            for (int ct = 0; ct < NT; ++ct) {
                short8 afrag = *(const short8*)(wp
                    + (size_t)(co_w0 + ct * 16 + nl) * (9 * CIN) + e * CIN + ci0 + quad * 8);
#pragma unroll
                for (int pg = 0; pg < 4; ++pg)
                    acc[pg][ct] = __builtin_amdgcn_mfma_f32_16x16x32_bf16(afrag, bfrag[pg], acc[pg][ct], 0, 0, 0);
            }
        }
    }

#pragma unroll
    for (int pg = 0; pg < 4; ++pg) {
        int px = x0 + pg * 16 + nl;
        unsigned short* op = out + ((size_t)row * WW + px) * COUT;
#pragma unroll
        for (int ct = 0; ct < NT; ++ct) {
            int cb = co_w0 + ct * 16 + quad * 4;
            ushort4 v;
            v.x = f2bf(fmaxf(acc[pg][ct][0] + bias[cb + 0], 0.f));
            v.y = f2bf(fmaxf(acc[pg][ct][1] + bias[cb + 1], 0.f));
            v.z = f2bf(fmaxf(acc[pg][ct][2] + bias[cb + 2], 0.f));
            v.w = f2bf(fmaxf(acc[pg][ct][3] + bias[cb + 3], 0.f));
            *(ushort4*)(op + cb) = v;
        }
    }
}

// global-average-pool sums over det3 output [HW][256] bf16 -> pooled[256]
__global__ __launch_bounds__(256) void pool_kernel(
    const unsigned short* __restrict__ d3, float* __restrict__ pooled)
{
    __shared__ float s_pool[256];
    int t = threadIdx.x;
    s_pool[t] = 0.f;
    __syncthreads();
    int co8 = (t & 31) * 8;
    int pxg = t >> 5;
    float sums[8];
#pragma unroll
    for (int j = 0; j < 8; ++j) sums[j] = 0.f;
    int base = blockIdx.x * 2304 + pxg;
    for (int i = 0; i < 288; ++i) {
        int px = base + i * 8;
        const uint4* p = (const uint4*)(d3 + (size_t)px * 256 + co8);
        uint4 v = *p;
        unsigned int w[4] = {v.x, v.y, v.z, v.w};
#pragma unroll
        for (int g = 0; g < 4; ++g) {
            sums[g*2+0] += bf2f((unsigned short)(w[g] & 0xFFFF));
            sums[g*2+1] += bf2f((unsigned short)(w[g] >> 16));
        }
    }
#pragma unroll
    for (int j = 0; j < 8; ++j) atomicAdd(&s_pool[co8 + j], sums[j]);
    __syncthreads();
    atomicAdd(&pooled[t], s_pool[t]);
}

__global__ void fc_argmax_kernel(const float* __restrict__ pooled,
                                 const float* __restrict__ fcw,
                                 const float* __restrict__ fcb,
                                 int* __restrict__ pred)
{
    int t = threadIdx.x;
    float m = pooled[t] * (1.0f / (float)HWSZ);
    float p0 = m * fcw[t];
    float p1 = m * fcw[256 + t];
    float p2 = m * fcw[512 + t];
    p0 = waveSum(p0); p1 = waveSum(p1); p2 = waveSum(p2);
    __shared__ float rr[3][4];
    int wid = t >> 6, lane = t & 63;
    if (lane == 0) { rr[0][wid] = p0; rr[1][wid] = p1; rr[2][wid] = p2; }
    __syncthreads();
    if (t == 0) {
        float l0 = rr[0][0] + rr[0][1] + rr[0][2] + rr[0][3] + fcb[0];
        float l1 = rr[1][0] + rr[1][1] + rr[1][2] + rr[1][3] + fcb[1];
        float l2 = rr[2][0] + rr[2][1] + rr[2][2] + rr[2][3] + fcb[2];
        int best = 0; float bv = l0;
        if (l1 > bv) { best = 1; bv = l1; }
        if (l2 > bv) { best = 2; bv = l2; }
        *pred = best;
    }
}

// ===========================================================================
// BRANCH convs — bf16 hi/lo 3-MFMA emulation (~fp19 per product; error ~1e-5).
// Gated: early-return when pred==0.
// ===========================================================================

// split weights OIHW fp32 -> [co][e][ci] bf16 hi + lo
__global__ __launch_bounds__(256) void wsplit_kernel(
    const float* __restrict__ w,
    unsigned short* __restrict__ hi, unsigned short* __restrict__ lo,
    int Cin, int total)
{
    int t = blockIdx.x * 256 + threadIdx.x;
    if (t >= total) return;
    int nine_cin = 9 * Cin;
    int co = t / nine_cin;
    int r = t - co * nine_cin;
    int e = r / Cin;
    int ci = r - e * Cin;
    float v = w[(size_t)co * nine_cin + ci * 9 + e];
    unsigned short h = f2bf(v);
    hi[t] = h;
    lo[t] = f2bf(v - bf2f(h));
}

// x all batches: NCHW fp32 -> NHWC bf16 hi + lo (gated)
__global__ __launch_bounds__(256) void xsplitb_kernel(
    const float* __restrict__ x, const int* __restrict__ predp,
    unsigned short* __restrict__ hi, unsigned short* __restrict__ lo)
{
    if (__builtin_amdgcn_readfirstlane(*predp) == 0) return;
    int p = blockIdx.x * 256 + threadIdx.x;
    if (p >= BB * HWSZ) return;
    int b = p / HWSZ, n = p % HWSZ;
    const float* sp = x + (size_t)b * 32 * HWSZ + n;
    unsigned short uh[32], ul[32];
#pragma unroll
    for (int c = 0; c < 32; ++c) {
        float v = sp[(size_t)c * HWSZ];
        unsigned short h = f2bf(v);
        uh[c] = h;
        ul[c] = f2bf(v - bf2f(h));
    }
    uint4* dh = (uint4*)(hi + (size_t)p * 32);
    uint4* dl = (uint4*)(lo + (size_t)p * 32);
#pragma unroll
    for (int g = 0; g < 4; ++g) {
        uint4 vh, vl;
        vh.x = (unsigned)uh[g*8+0] | ((unsigned)uh[g*8+1] << 16);
        vh.y = (unsigned)uh[g*8+2] | ((unsigned)uh[g*8+3] << 16);
        vh.z = (unsigned)uh[g*8+4] | ((unsigned)uh[g*8+5] << 16);
        vh.w = (unsigned)uh[g*8+6] | ((unsigned)uh[g*8+7] << 16);
        vl.x = (unsigned)ul[g*8+0] | ((unsigned)ul[g*8+1] << 16);
        vl.y = (unsigned)ul[g*8+2] | ((unsigned)ul[g*8+3] << 16);
        vl.z = (unsigned)ul[g*8+4] | ((unsigned)ul[g*8+5] << 16);
        vl.w = (unsigned)ul[g*8+6] | ((unsigned)ul[g*8+7] << 16);
        dh[g] = vh;
        dl[g] = vl;
    }
}

// branch 3x3 conv, pad=1, bias+ReLU, hi/lo bf16 in, 3-MFMA per tap-chunk.
// OUTMODE 0: write bf16 hi/lo NHWC (t1). OUTMODE 1: write fp32 NCHW (xb).
template<int CIN, int COUT, int OUTMODE>
__global__ __launch_bounds__(256) void bconv_kernel(
    const unsigned short* __restrict__ in_hi, const unsigned short* __restrict__ in_lo,
    const unsigned short* __restrict__ wAh, const unsigned short* __restrict__ wAl,
    const unsigned short* __restrict__ wBh, const unsigned short* __restrict__ wBl,
    const float* __restrict__ bA, const float* __restrict__ bB,
    const int* __restrict__ predp,
    unsigned short* __restrict__ out_hi, unsigned short* __restrict__ out_lo,
    float* __restrict__ out_f32)
{
    const int p = __builtin_amdgcn_readfirstlane(*predp);
    if (p == 0) return;
    const unsigned short* whi = (p == 1) ? wAh : wBh;
    const unsigned short* wlo = (p == 1) ? wAl : wBl;
    const float* bias = (p == 1) ? bA : bB;

    constexpr int NPG = (COUT == 64) ? 4 : 2;
    __shared__ unsigned short s_hi[198 * LPAD];
    __shared__ unsigned short s_lo[198 * LPAD];

    const int tid  = threadIdx.x;
    const int lane = tid & 63;
    const int wave = tid >> 6;
    const int nl   = lane & 15;
    const int quad = lane >> 4;
    const int row  = blockIdx.x / 6;
    const int x0   = (blockIdx.x % 6) * 64;
    const int b    = blockIdx.y;
    const int co_w0 = (COUT == 64) ? wave * 16 : (wave & 1) * 16;
    const int pg0   = (COUT == 64) ? 0 : (wave >> 1) * 2;

    f32x4 acc[NPG];
#pragma unroll
    for (int g = 0; g < NPG; ++g) acc[g] = (f32x4){0.f,0.f,0.f,0.f};

    const unsigned short* ibh = in_hi + (size_t)b * HWSZ * CIN;
    const unsigned short* ibl = in_lo + (size_t)b * HWSZ * CIN;

#pragma unroll
    for (int ci0 = 0; ci0 < CIN; ci0 += 32) {
        __syncthreads();
        for (int idx = tid; idx < 792; idx += 256) {
            int qs   = idx & 3;
            int cell = idx >> 2;
            int px   = cell % 66;
            int r    = cell / 66;
            int gy   = row + r - 1;
            int gx   = x0 + px - 1;
            uint4 vh = {0u,0u,0u,0u}, vl = {0u,0u,0u,0u};
            if ((unsigned)gy < (unsigned)HH && (unsigned)gx < (unsigned)WW) {
                size_t base = (size_t)(gy * WW + gx) * CIN + ci0 + qs * 8;
                vh = *(const uint4*)(ibh + base);
                vl = *(const uint4*)(ibl + base);
            }
            *(uint4*)(s_hi + cell * LPAD + qs * 8) = vh;
            *(uint4*)(s_lo + cell * LPAD + qs * 8) = vl;
        }
        __syncthreads();
#pragma unroll
        for (int e = 0; e < 9; ++e) {
            const int er = e / 3, ec = e % 3;
            size_t woff = (size_t)(co_w0 + nl) * (9 * CIN) + e * CIN + ci0 + quad * 8;
            short8 ah = *(const short8*)(whi + woff);
            short8 al = *(const short8*)(wlo + woff);
#pragma unroll
            for (int g = 0; g < NPG; ++g) {
                int cell = er * 66 + (pg0 + g) * 16 + nl + ec;
                short8 bh = *(const short8*)(s_hi + cell * LPAD + quad * 8);
                short8 bl = *(const short8*)(s_lo + cell * LPAD + quad * 8);
                acc[g] = __builtin_amdgcn_mfma_f32_16x16x32_bf16(ah, bh, acc[g], 0, 0, 0);
                acc[g] = __builtin_amdgcn_mfma_f32_16x16x32_bf16(ah, bl, acc[g], 0, 0, 0);
                acc[g] = __builtin_amdgcn_mfma_f32_16x16x32_bf16(al, bh, acc[g], 0, 0, 0);
            }
        }
    }

    const int cb = co_w0 + quad * 4;
#pragma unroll
    for (int g = 0; g < NPG; ++g) {
        int px = x0 + (pg0 + g) * 16 + nl;
        float r0 = fmaxf(acc[g][0] + bias[cb + 0], 0.f);
        float r1 = fmaxf(acc[g][1] + bias[cb + 1], 0.f);
        float r2 = fmaxf(acc[g][2] + bias[cb + 2], 0.f);
        float r3 = fmaxf(acc[g][3] + bias[cb + 3], 0.f);
        if (OUTMODE == 0) {
            size_t base = ((size_t)b * HWSZ + row * WW + px) * COUT + cb;
            ushort4 vh, vl;
            unsigned short h;
            h = f2bf(r0); vh.x = h; vl.x = f2bf(r0 - bf2f(h));
            h = f2bf(r1); vh.y = h; vl.y = f2bf(r1 - bf2f(h));
            h = f2bf(r2); vh.z = h; vl.z = f2bf(r2 - bf2f(h));
            h = f2bf(r3); vh.w = h; vl.w = f2bf(r3 - bf2f(h));
            *(ushort4*)(out_hi + base) = vh;
            *(ushort4*)(out_lo + base) = vl;
        } else {
            size_t sp = (size_t)row * WW + px;
            out_f32[((size_t)b * COUT + cb + 0) * HWSZ + sp] = r0;
            out_f32[((size_t)b * COUT + cb + 1) * HWSZ + sp] = r1;
            out_f32[((size_t)b * COUT + cb + 2) * HWSZ + sp] = r2;
            out_f32[((size_t)b * COUT + cb + 3) * HWSZ + sp] = r3;
        }
    }
}

// ===========================================================================
// NUMERIC CHAIN — fp32
// ===========================================================================
__global__ __launch_bounds__(256) void lnpw_kernel(
    const float* __restrict__ x, const float* __restrict__ xb,
    const int* __restrict__ predp,
    const float* __restrict__ lnw, const float* __restrict__ lnb,
    const float* __restrict__ pww,
    float* __restrict__ qkvp)
{
    int p = blockIdx.x * 256 + threadIdx.x;
    if (p >= BB * HWSZ) return;
    int pr = __builtin_amdgcn_readfirstlane(*predp);
    const float* src = (pr == 0) ? x : xb;
    int b = p / HWSZ, n = p % HWSZ;
    const float* sp = src + (size_t)b * 32 * HWSZ + n;
    float v[32];
    float mean = 0.f;
#pragma unroll
    for (int c = 0; c < 32; ++c) { v[c] = sp[(size_t)c * HWSZ]; mean += v[c]; }
    mean *= (1.f / 32.f);
    float var = 0.f;
#pragma unroll
    for (int c = 0; c < 32; ++c) { float d = v[c] - mean; var += d * d; }
    var *= (1.f / 32.f);
    float rstd = rsqrtf(var + 1e-6f);
#pragma unroll
    for (int c = 0; c < 32; ++c)
        v[c] = (v[c] - mean) * rstd * lnw[c] + lnb[c];

    float acc[96];
#pragma unroll
    for (int co = 0; co < 96; ++co) acc[co] = 0.f;
    for (int ci = 0; ci < 32; ++ci) {
        float va = v[ci];
#pragma unroll
        for (int co = 0; co < 96; ++co)
            acc[co] = fmaf(pww[co * 32 + ci], va, acc[co]);
    }
    float* op = qkvp + (size_t)b * 96 * HWSZ + n;
#pragma unroll
    for (int co = 0; co < 96; ++co) op[(size_t)co * HWSZ] = acc[co];
}

// q/k depthwise-conv-on-the-fly + attention stats.
// 4 px/thread; hand-unrolled even/odd (A/B) register-set pipeline keeps one
// full channel's 9 load instructions in flight ahead of the consuming FMA
// chain. All loads unconditional (clamped addresses, select-to-zero after),
// all indices compile-time constant.
// NOTE: plain __launch_bounds__(256) — the (256,4) annotation empirically
// capped the allocator at 64 VGPR on this toolchain (R2/R3: both 64 VGPR +
// ~117 MB scratch WRITE_SIZE). lnpw (live set >=128 fl) gets full registers
// under plain (256), so the default heuristic grants what the pipeline needs.
__global__ __launch_bounds__(256) void qkdwstats_kernel(
    const float* __restrict__ qkvp, const float* __restrict__ dww,
    float* __restrict__ stats)
{
    int bh = blockIdx.y;
    int b = bh >> 3, h = bh & 7;
    const float* qbase = qkvp + ((size_t)b * 96 + h * 4) * HWSZ;
    const float* kbase = qkvp + ((size_t)b * 96 + 32 + h * 4) * HWSZ;
    const float* wq = dww + (h * 4) * 9;
    const float* wk = dww + (32 + h * 4) * 9;

    int g = blockIdx.x * 256 + threadIdx.x;     // [0, 36864)
    int y  = g / 96;
    int xg = (g - y * 96) * 4;

    float s[16], qn[4], kn[4];
#pragma unroll
    for (int i = 0; i < 16; ++i) s[i] = 0.f;
#pragma unroll
    for (int i = 0; i < 4; ++i) { qn[i] = 0.f; kn[i] = 0.f; }

    f32x4 mA[3]; float eA0[3], eA1[3];
    f32x4 mB[3]; float eB0[3], eB1[3];
    float q[4][4];
    float k4[4];

    // ---- q channels: A/B pipelined ----
    dwload4v(qbase,                  y, xg, mA, eA0, eA1);   // q0 -> A
    dwload4v(qbase + (size_t)HWSZ,   y, xg, mB, eB0, eB1);   // q1 -> B
    dwapply4v(mA, eA0, eA1, wq + 0,  q[0]);
    dwload4v(qbase + (size_t)2*HWSZ, y, xg, mA, eA0, eA1);   // q2 -> A
    dwapply4v(mB, eB0, eB1, wq + 9,  q[1]);
    dwload4v(qbase + (size_t)3*HWSZ, y, xg, mB, eB0, eB1);   // q3 -> B
    dwapply4v(mA, eA0, eA1, wq + 18, q[2]);
    dwload4v(kbase,                  y, xg, mA, eA0, eA1);   // k0 -> A
    dwapply4v(mB, eB0, eB1, wq + 27, q[3]);
#pragma unroll
    for (int c = 0; c < 4; ++c)
#pragma unroll
        for (int j = 0; j < 4; ++j) qn[c] = fmaf(q[c][j], q[c][j], qn[c]);

    // ---- k channels: A/B pipelined, fused stats ----
    dwload4v(kbase + (size_t)HWSZ,   y, xg, mB, eB0, eB1);   // k1 -> B
    dwapply4v(mA, eA0, eA1, wk + 0, k4);
#pragma unroll
    for (int j = 0; j < 4; ++j) kn[0] = fmaf(k4[j], k4[j], kn[0]);
#pragma unroll
    for (int c = 0; c < 4; ++c)
#pragma unroll
        for (int j = 0; j < 4; ++j) s[c*4+0] = fmaf(q[c][j], k4[j], s[c*4+0]);

    dwload4v(kbase + (size_t)2*HWSZ, y, xg, mA, eA0, eA1);   // k2 -> A
    dwapply4v(mB, eB0, eB1, wk + 9, k4);
#pragma unroll
    for (int j = 0; j < 4; ++j) kn[1] = fmaf(k4[j], k4[j], kn[1]);
#pragma unroll
    for (int c = 0; c < 4; ++c)
#pragma unroll
        for (int j = 0; j < 4; ++j) s[c*4+1] = fmaf(q[c][j], k4[j], s[c*4+1]);

    dwload4v(kbase + (size_t)3*HWSZ, y, xg, mB, eB0, eB1);   // k3 -> B
    dwapply4v(mA, eA0, eA1, wk + 18, k4);
#pragma unroll
    for (int j = 0; j < 4; ++j) kn[2] = fmaf(k4[j], k4[j], kn[2]);
#pragma unroll
    for (int c = 0; c < 4; ++c)
#pragma unroll
        for (int j = 0; j < 4; ++j) s[c*4+2] = fmaf(q[c][j], k4[j], s[c*4+2]);

    dwapply4v(mB, eB0, eB1, wk + 27, k4);
#pragma unroll
    for (int j = 0; j < 4; ++j) kn[3] = fmaf(k4[j], k4[j], kn[3]);
#pragma unroll
    for (int c = 0; c < 4; ++c)
#pragma unroll
        for (int j = 0; j < 4; ++j) s[c*4+3] = fmaf(q[c][j], k4[j], s[c*4+3]);

    float* st = stats + bh * 24;
    int lane = threadIdx.x & 63;
#pragma unroll
    for (int i = 0; i < 16; ++i) {
        float v = waveSum(s[i]);
        if (lane == 0) atomicAdd(&st[i], v);
    }
#pragma unroll
    for (int i = 0; i < 4; ++i) {
        float v = waveSum(qn[i]);
        if (lane == 0) atomicAdd(&st[16 + i], v);
        float u = waveSum(kn[i]);
        if (lane == 0) atomicAdd(&st[20 + i], u);
    }
}

// v depthwise conv into q-channel slots. 8 px/thread (R1-proven form).
__global__ __launch_bounds__(256) void vdw_kernel(
    float* __restrict__ qkvp, const float* __restrict__ dww)
{
    int t = blockIdx.x * 256 + threadIdx.x;     // [0, 2359296)
    int bc = t / 18432;
    int g  = t - bc * 18432;
    int b = bc >> 5, c = bc & 31;
    int y  = g / 48;
    int xg = (g - y * 48) * 8;
    const float* ip = qkvp + ((size_t)b * 96 + 64 + c) * HWSZ;
    const float* wc = dww + (64 + c) * 9;
    float o[8];
    dwconv8(ip, wc, y, xg, o);
    float* op = qkvp + ((size_t)b * 96 + c) * HWSZ + (size_t)y * WW + xg;
    f32x4 v0 = {o[0], o[1], o[2], o[3]};
    f32x4 v1 = {o[4], o[5], o[6], o[7]};
    *(f32x4*)op = v0;
    *(f32x4*)(op + 4) = v1;
}

__global__ void attnmb_kernel(const float* __restrict__ stats,
                              const float* __restrict__ temp,
                              const float* __restrict__ projw,
                              float* __restrict__ Mb)
{
    __shared__ float attn_s[4][8][4][4];
    int t = threadIdx.x;
    if (t < 128) {
        int b = t >> 5;
        int h = (t >> 2) & 7;
        int c = t & 3;
        const float* st = stats + (b * 8 + h) * 24;
        float qn = fmaxf(sqrtf(st[16 + c]), 1e-12f);
        float tp = temp[h];
        float raw[4];
#pragma unroll
        for (int d = 0; d < 4; ++d) {
            float kn = fmaxf(sqrtf(st[20 + d]), 1e-12f);
            raw[d] = st[c * 4 + d] / (qn * kn) * tp;
        }
        float m = fmaxf(fmaxf(raw[0], raw[1]), fmaxf(raw[2], raw[3]));
        float e0 = expf(raw[0] - m), e1 = expf(raw[1] - m);
        float e2 = expf(raw[2] - m), e3 = expf(raw[3] - m);
        float inv = 1.f / (e0 + e1 + e2 + e3);
        attn_s[b][h][c][0] = e0 * inv;
        attn_s[b][h][c][1] = e1 * inv;
        attn_s[b][h][c][2] = e2 * inv;
        attn_s[b][h][c][3] = e3 * inv;
    }
    __syncthreads();
    for (int idx = t; idx < 4096; idx += 256) {
        int b = idx >> 10;
        int r = idx & 1023;
        int co = r >> 5;
        int j = r & 31;
        int h = j >> 2;
        int d = j & 3;
        float m = 0.f;
#pragma unroll
        for (int l = 0; l < 4; ++l)
            m = fmaf(projw[co * 32 + h * 4 + l], attn_s[b][h][l][d], m);
        Mb[idx] = m;
    }
}

__global__ __launch_bounds__(256) void e1_kernel(
    float* __restrict__ qkvp, const float* __restrict__ x,
    const float* __restrict__ xb, const int* __restrict__ predp,
    const float* __restrict__ Mb, const float* __restrict__ ff1w)
{
    int p = blockIdx.x * 256 + threadIdx.x;
    if (p >= BB * HWSZ) return;
    int pr = __builtin_amdgcn_readfirstlane(*predp);
    const float* src = (pr == 0) ? x : xb;
    int b = p / HWSZ, n = p % HWSZ;
    float* vp = qkvp + (size_t)b * 96 * HWSZ + n;
    const float* Mbb = Mb + b * 1024;
    float y[32];
#pragma unroll
    for (int c = 0; c < 32; ++c) y[c] = 0.f;
    for (int j = 0; j < 32; ++j) {
        float vj = vp[(size_t)j * HWSZ];
#pragma unroll
        for (int co = 0; co < 32; ++co)
            y[co] = fmaf(Mbb[co * 32 + j], vj, y[co]);
    }
    const float* xp = src + (size_t)b * 32 * HWSZ + n;
#pragma unroll
    for (int c = 0; c < 32; ++c) y[c] += xp[(size_t)c * HWSZ];
    for (int co = 0; co < 32; ++co) {
        float s = 0.f;
#pragma unroll
        for (int ci = 0; ci < 32; ++ci)
            s = fmaf(ff1w[co * 32 + ci], y[ci], s);
        vp[(size_t)co * HWSZ] = gelu_exact(s);
    }
}

// final depthwise conv + gelu. 8 px/thread (R1-proven form).
__global__ __launch_bounds__(256) void fdw_kernel(
    const float* __restrict__ z1, const float* __restrict__ w,
    float* __restrict__ out)
{
    int t = blockIdx.x * 256 + threadIdx.x;     // [0, 2359296)
    int bc = t / 18432;
    int g  = t - bc * 18432;
    int b = bc >> 5, c = bc & 31;
    int y  = g / 48;
    int xg = (g - y * 48) * 8;
    const float* ip = z1 + ((size_t)b * 96 + c) * HWSZ;
    const float* wc = w + c * 9;
    float o[8];
    dwconv8(ip, wc, y, xg, o);
#pragma unroll
    for (int j = 0; j < 8; ++j) o[j] = gelu_exact(o[j]);
    float* op = out + ((size_t)b * 32 + c) * HWSZ + (size_t)y * WW + xg;
    f32x4 v0 = {o[0], o[1], o[2], o[3]};
    f32x4 v1 = {o[4], o[5], o[6], o[7]};
    *(f32x4*)op = v0;
    *(f32x4*)(op + 4) = v1;
}

// ---------------------------------------------------------------------------
extern "C" void kernel_launch(void* const* d_in, const int* in_sizes, int n_in,
                              void* d_out, int out_size, void* d_ws, size_t ws_size,
                              hipStream_t stream)
{
    (void)in_sizes; (void)n_in; (void)out_size; (void)ws_size;
    const float* x      = (const float*)d_in[0];
    const float* ln_w   = (const float*)d_in[1];
    const float* ln_b   = (const float*)d_in[2];
    const float* temp   = (const float*)d_in[3];
    const float* pw_w   = (const float*)d_in[4];
    const float* dw_w   = (const float*)d_in[5];
    const float* proj_w = (const float*)d_in[6];
    const float* ff1_w  = (const float*)d_in[7];
    const float* ffdw_w = (const float*)d_in[8];
    const float* det_w1 = (const float*)d_in[9];
    const float* det_b1 = (const float*)d_in[10];
    const float* det_w2 = (const float*)d_in[11];
    const float* det_b2 = (const float*)d_in[12];
    const float* det_w3 = (const float*)d_in[13];
    const float* det_b3 = (const float*)d_in[14];
    const float* fc_w   = (const float*)d_in[15];
    const float* fc_b   = (const float*)d_in[16];
    const float* hvi_w1 = (const float*)d_in[17];
    const float* hvi_b1 = (const float*)d_in[18];
    const float* hvi_w2 = (const float*)d_in[19];
    const float* hvi_b2 = (const float*)d_in[20];
    const float* ycc_w1 = (const float*)d_in[21];
    const float* ycc_b1 = (const float*)d_in[22];
    const float* ycc_w2 = (const float*)d_in[23];
    const float* ycc_b2 = (const float*)d_in[24];

    float* ws     = (float*)d_ws;
    float* misc   = ws + OFF_MISC;
    float* A      = ws + OFF_A;
    // det phase
    unsigned short* x0bf  = (unsigned short*)A;
    unsigned short* f1bf  = (unsigned short*)(A + 2359296);
    unsigned short* f2bf  = (unsigned short*)(A + 7077888);
    unsigned short* d3out = (unsigned short*)(A + 16515072);
    unsigned short* w1p   = (unsigned short*)(A + 56423104);
    unsigned short* w2p   = (unsigned short*)(A + 56432320);
    unsigned short* w3p   = (unsigned short*)(A + 56469184);
    // branch phase
    unsigned short* xs_hi = (unsigned short*)A;
    unsigned short* xs_lo = (unsigned short*)(A + 9437184);
    unsigned short* t1_hi = (unsigned short*)(A + 18874368);
    unsigned short* t1_lo = (unsigned short*)(A + 37748736);
    unsigned short* bw    = (unsigned short*)(ws + OFF_BW);
    unsigned short* bw_h1h = bw;            unsigned short* bw_h1l = bw + 18432;
    unsigned short* bw_y1h = bw + 36864;    unsigned short* bw_y1l = bw + 55296;
    unsigned short* bw_h2h = bw + 73728;    unsigned short* bw_h2l = bw + 92160;
    unsigned short* bw_y2h = bw + 110592;   unsigned short* bw_y2l = bw + 129024;
    // qkv phase
    float* qkvp   = A;
    float* xb     = (float*)d_out;
    float* pooled = misc + MISC_POOLED;
    int*   pred   = (int*)(misc + MISC_PRED);
    float* stats  = misc + MISC_STATS;
    float* Mb     = misc + MISC_MB;
    float* out    = (float*)d_out;

    hipMemsetAsync(misc, 0, 2048 * sizeof(float), stream);

    dim3 blk(256);
    // ---- weight + input conversion ----
    wcvt_kernel<<<(18432 + 255) / 256, blk, 0, stream>>>(det_w1, w1p, 32, 18432);
    wcvt_kernel<<<(73728 + 255) / 256, blk, 0, stream>>>(det_w2, w2p, 64, 73728);
    wcvt_kernel<<<(294912 + 255) / 256, blk, 0, stream>>>(det_w3, w3p, 128, 294912);
    xcvt_kernel<<<576, blk, 0, stream>>>(x, x0bf);
    wsplit_kernel<<<72, blk, 0, stream>>>(hvi_w1, bw_h1h, bw_h1l, 32, 18432);
    wsplit_kernel<<<72, blk, 0, stream>>>(ycc_w1, bw_y1h, bw_y1l, 32, 18432);
    wsplit_kernel<<<72, blk, 0, stream>>>(hvi_w2, bw_h2h, bw_h2l, 64, 18432);
    wsplit_kernel<<<72, blk, 0, stream>>>(ycc_w2, bw_y2h, bw_y2l, 64, 18432);

    // ---- detector (batch 0 only; feeds argmax) ----
    mfma_conv2_kernel<32, 64>  <<<2304, blk, 0, stream>>>(x0bf, w1p, det_b1, f1bf);
    mfma_conv2_kernel<64, 128> <<<2304, blk, 0, stream>>>(f1bf, w2p, det_b2, f2bf);
    mfma_conv2_kernel<128, 256><<<2304, blk, 0, stream>>>(f2bf, w3p, det_b3, d3out);
    pool_kernel<<<64, blk, 0, stream>>>(d3out, pooled);
    fc_argmax_kernel<<<1, 256, 0, stream>>>(pooled, fc_w, fc_b, pred);

    // ---- gated color-space branch (bf16 hi/lo 3-MFMA; ~fp32 accuracy) ----
    xsplitb_kernel<<<2304, blk, 0, stream>>>(x, pred, xs_hi, xs_lo);
    bconv_kernel<32, 64, 0><<<dim3(2304, BB), blk, 0, stream>>>(
        xs_hi, xs_lo, bw_h1h, bw_h1l, bw_y1h, bw_y1l, hvi_b1, ycc_b1, pred,
        t1_hi, t1_lo, nullptr);
    bconv_kernel<64, 32, 1><<<dim3(2304, BB), blk, 0, stream>>>(
        t1_hi, t1_lo, bw_h2h, bw_h2l, bw_y2h, bw_y2l, hvi_b2, ycc_b2, pred,
        nullptr, nullptr, xb);

    // ---- fused LN + pw(1x1) -> qkvp ----
    lnpw_kernel<<<2304, blk, 0, stream>>>(x, xb, pred, ln_w, ln_b, pw_w, qkvp);

    // ---- q/k dw-on-the-fly + stats; v dw into q-channel slots ----
    qkdwstats_kernel<<<dim3(144, 32), blk, 0, stream>>>(qkvp, dw_w, stats);
    vdw_kernel<<<9216, blk, 0, stream>>>(qkvp, dw_w);
    attnmb_kernel<<<1, 256, 0, stream>>>(stats, temp, proj_w, Mb);

    // ---- epilogue ----
    e1_kernel<<<2304, blk, 0, stream>>>(qkvp, x, xb, pred, Mb, ff1_w);
    fdw_kernel<<<9216, blk, 0, stream>>>(qkvp, ffdw_w, out);
}

// Round 5
// 1238.907 us; speedup vs baseline: 1.4031x; 1.4031x over previous
//
#include <hip/hip_runtime.h>
#include <hip/hip_bf16.h>
#include <math.h>

#define HH 384
#define WW 384
#define HWSZ (HH*WW)   // 147456
#define BB 4

typedef __attribute__((ext_vector_type(8))) short short8;
typedef __attribute__((ext_vector_type(4))) float f32x4;

// ---- workspace layout (float offsets). TOTAL: 16384 + 56,623,104 + 73,728
// = 56,713,216 fl = 226.9 MB (226.6 proved OK in r2-r4).
static const size_t OFF_MISC = 0;        // 16384 floats
static const size_t OFF_A    = 16384;    // big region, 56,623,104 floats
static const size_t OFF_BW   = OFF_A + 56623104;   // 73,728 fl branch weights
// region-A sequenced reuse (float offsets within A):
//   det phase:  x0 bf16   @0          ; f1 bf16 @2,359,296 ; f2 bf16 @7,077,888
//               d3out bf16@16,515,072 (ends 35,389,440)
//               det W' bf16 @56,423,104 (ends 56,616,640)
//   branch:     xs_hi @0 (9.44M fl) ; xs_lo @9.44M ; t1_hi @18.87M ; t1_lo @37.75M
//               (t1_lo overwrites det W' - dead by then; xb lives in d_out)
//   qkv:        qkvp fp32 @0 (56,623,104 fl)
// misc (float offsets):
static const size_t MISC_POOLED = 0;     // 256 floats
static const size_t MISC_PRED   = 1024;  // 1 int
static const size_t MISC_STATS  = 1056;  // 768 floats
static const size_t MISC_MB     = 2048;  // 4096 floats

#define LPAD 40   // LDS row stride in ushorts: (cell*80+quad*16)/4 %32 covers
                  // all 32 banks 2-way (free) vs stride 32's 8-way conflict.

__device__ __forceinline__ float waveSum(float v) {
#pragma unroll
    for (int off = 32; off > 0; off >>= 1) v += __shfl_down(v, off);
    return v;
}

__device__ __forceinline__ float gelu_exact(float v) {
    return 0.5f * v * (1.0f + erff(v * 0.70710678118654752f));
}

__device__ __forceinline__ unsigned short f2bf(float f) {
    __hip_bfloat16 h = __float2bfloat16(f);
    return *(unsigned short*)&h;
}
__device__ __forceinline__ float bf2f(unsigned short u) {
    unsigned int b = ((unsigned int)u) << 16;
    return __uint_as_float(b);
}

// 3x3 depthwise conv, zero-pad, 8 consecutive pixels of row y at column xg
// (xg multiple of 8). Proven no-spill form (R1: 48 VGPR, WRITE_SIZE clean).
__device__ __forceinline__ void dwconv8(const float* __restrict__ base,
                                        const float* __restrict__ w9,
                                        int y, int xg, float o[8])
{
#pragma unroll
    for (int j = 0; j < 8; ++j) o[j] = 0.f;
#pragma unroll
    for (int dy = 0; dy < 3; ++dy) {
        int gy = y + dy - 1;
        if ((unsigned)gy >= (unsigned)HH) continue;
        const float* rp = base + (size_t)gy * WW + xg;
        f32x4 m0 = *(const f32x4*)(rp);
        f32x4 m1 = *(const f32x4*)(rp + 4);
        float r0 = (xg > 0) ? rp[-1] : 0.f;
        float r9 = (xg + 8 < WW) ? rp[8] : 0.f;
        float r[10] = {r0, m0[0], m0[1], m0[2], m0[3],
                           m1[0], m1[1], m1[2], m1[3], r9};
        float w0 = w9[dy * 3 + 0], w1 = w9[dy * 3 + 1], w2 = w9[dy * 3 + 2];
#pragma unroll
        for (int j = 0; j < 8; ++j)
            o[j] = fmaf(r[j], w0, fmaf(r[j + 1], w1, fmaf(r[j + 2], w2, o[j])));
    }
}

// ===========================================================================
// DETECTOR PATH (bf16 MFMA) — only argmax(logits[0]) is consumed.
// ===========================================================================

// x batch0: NCHW fp32 -> NHWC bf16
__global__ __launch_bounds__(256) void xcvt_kernel(
    const float* __restrict__ x, unsigned short* __restrict__ x0)
{
    int px = blockIdx.x * 256 + threadIdx.x;
    if (px >= HWSZ) return;
    unsigned short u[32];
#pragma unroll
    for (int c = 0; c < 32; ++c) u[c] = f2bf(x[(size_t)c * HWSZ + px]);
    uint4* dst = (uint4*)(x0 + (size_t)px * 32);
#pragma unroll
    for (int g = 0; g < 4; ++g) {
        uint4 v;
        v.x = (unsigned)u[g*8+0] | ((unsigned)u[g*8+1] << 16);
        v.y = (unsigned)u[g*8+2] | ((unsigned)u[g*8+3] << 16);
        v.z = (unsigned)u[g*8+4] | ((unsigned)u[g*8+5] << 16);
        v.w = (unsigned)u[g*8+6] | ((unsigned)u[g*8+7] << 16);
        dst[g] = v;
    }
}

// weights OIHW fp32 -> [co][e=dy*3+dx][ci] bf16
__global__ __launch_bounds__(256) void wcvt_kernel(
    const float* __restrict__ w, unsigned short* __restrict__ wp,
    int Cin, int total)
{
    int t = blockIdx.x * 256 + threadIdx.x;
    if (t >= total) return;
    int nine_cin = 9 * Cin;
    int co = t / nine_cin;
    int r = t - co * nine_cin;
    int e = r / Cin;
    int ci = r - e * Cin;
    wp[t] = f2bf(w[(size_t)co * nine_cin + ci * 9 + e]);
}

// implicit-GEMM 3x3 conv, pad=1, bias+ReLU, NHWC bf16 (detector).
template<int CIN, int COUT>
__global__ __launch_bounds__(256) void mfma_conv2_kernel(
    const unsigned short* __restrict__ in,
    const unsigned short* __restrict__ wp,
    const float* __restrict__ bias,
    unsigned short* __restrict__ out)
{
    constexpr int NT = COUT / 64;
    __shared__ unsigned short s_in[198 * LPAD];

    const int tid  = threadIdx.x;
    const int lane = tid & 63;
    const int wave = tid >> 6;
    const int nl   = lane & 15;
    const int quad = lane >> 4;
    const int row  = blockIdx.x / 6;
    const int x0   = (blockIdx.x % 6) * 64;
    const int co_w0 = wave * (COUT / 4);

    f32x4 acc[4][NT];
#pragma unroll
    for (int pg = 0; pg < 4; ++pg)
#pragma unroll
        for (int ct = 0; ct < NT; ++ct) acc[pg][ct] = (f32x4){0.f,0.f,0.f,0.f};

#pragma unroll
    for (int ci0 = 0; ci0 < CIN; ci0 += 32) {
        __syncthreads();
        for (int idx = tid; idx < 792; idx += 256) {
            int qs   = idx & 3;
            int cell = idx >> 2;
            int px   = cell % 66;
            int r    = cell / 66;
            int gy   = row + r - 1;
            int gx   = x0 + px - 1;
            uint4 v = {0u,0u,0u,0u};
            if ((unsigned)gy < (unsigned)HH && (unsigned)gx < (unsigned)WW)
                v = *(const uint4*)(in + (size_t)(gy * WW + gx) * CIN + ci0 + qs * 8);
            *(uint4*)(s_in + cell * LPAD + qs * 8) = v;
        }
        __syncthreads();
#pragma unroll
        for (int e = 0; e < 9; ++e) {
            const int er = e / 3, ec = e % 3;
            short8 bfrag[4];
#pragma unroll
            for (int pg = 0; pg < 4; ++pg)
                bfrag[pg] = *(const short8*)(s_in + ((er * 66 + pg * 16 + nl + ec) * LPAD + quad * 8));
#pragma unroll
            for (int ct = 0; ct < NT; ++ct) {
                short8 afrag = *(const short8*)(wp
                    + (size_t)(co_w0 + ct * 16 + nl) * (9 * CIN) + e * CIN + ci0 + quad * 8);
#pragma unroll
                for (int pg = 0; pg < 4; ++pg)
                    acc[pg][ct] = __builtin_amdgcn_mfma_f32_16x16x32_bf16(afrag, bfrag[pg], acc[pg][ct], 0, 0, 0);
            }
        }
    }

#pragma unroll
    for (int pg = 0; pg < 4; ++pg) {
        int px = x0 + pg * 16 + nl;
        unsigned short* op = out + ((size_t)row * WW + px) * COUT;
#pragma unroll
        for (int ct = 0; ct < NT; ++ct) {
            int cb = co_w0 + ct * 16 + quad * 4;
            ushort4 v;
            v.x = f2bf(fmaxf(acc[pg][ct][0] + bias[cb + 0], 0.f));
            v.y = f2bf(fmaxf(acc[pg][ct][1] + bias[cb + 1], 0.f));
            v.z = f2bf(fmaxf(acc[pg][ct][2] + bias[cb + 2], 0.f));
            v.w = f2bf(fmaxf(acc[pg][ct][3] + bias[cb + 3], 0.f));
            *(ushort4*)(op + cb) = v;
        }
    }
}

// global-average-pool sums over det3 output [HW][256] bf16 -> pooled[256]
__global__ __launch_bounds__(256) void pool_kernel(
    const unsigned short* __restrict__ d3, float* __restrict__ pooled)
{
    __shared__ float s_pool[256];
    int t = threadIdx.x;
    s_pool[t] = 0.f;
    __syncthreads();
    int co8 = (t & 31) * 8;
    int pxg = t >> 5;
    float sums[8];
#pragma unroll
    for (int j = 0; j < 8; ++j) sums[j] = 0.f;
    int base = blockIdx.x * 2304 + pxg;
    for (int i = 0; i < 288; ++i) {
        int px = base + i * 8;
        const uint4* p = (const uint4*)(d3 + (size_t)px * 256 + co8);
        uint4 v = *p;
        unsigned int w[4] = {v.x, v.y, v.z, v.w};
#pragma unroll
        for (int g = 0; g < 4; ++g) {
            sums[g*2+0] += bf2f((unsigned short)(w[g] & 0xFFFF));
            sums[g*2+1] += bf2f((unsigned short)(w[g] >> 16));
        }
    }
#pragma unroll
    for (int j = 0; j < 8; ++j) atomicAdd(&s_pool[co8 + j], sums[j]);
    __syncthreads();
    atomicAdd(&pooled[t], s_pool[t]);
}

__global__ void fc_argmax_kernel(const float* __restrict__ pooled,
                                 const float* __restrict__ fcw,
                                 const float* __restrict__ fcb,
                                 int* __restrict__ pred)
{
    int t = threadIdx.x;
    float m = pooled[t] * (1.0f / (float)HWSZ);
    float p0 = m * fcw[t];
    float p1 = m * fcw[256 + t];
    float p2 = m * fcw[512 + t];
    p0 = waveSum(p0); p1 = waveSum(p1); p2 = waveSum(p2);
    __shared__ float rr[3][4];
    int wid = t >> 6, lane = t & 63;
    if (lane == 0) { rr[0][wid] = p0; rr[1][wid] = p1; rr[2][wid] = p2; }
    __syncthreads();
    if (t == 0) {
        float l0 = rr[0][0] + rr[0][1] + rr[0][2] + rr[0][3] + fcb[0];
        float l1 = rr[1][0] + rr[1][1] + rr[1][2] + rr[1][3] + fcb[1];
        float l2 = rr[2][0] + rr[2][1] + rr[2][2] + rr[2][3] + fcb[2];
        int best = 0; float bv = l0;
        if (l1 > bv) { best = 1; bv = l1; }
        if (l2 > bv) { best = 2; bv = l2; }
        *pred = best;
    }
}

// ===========================================================================
// BRANCH convs — bf16 hi/lo 3-MFMA emulation (~fp19 per product; error ~1e-5).
// Gated: early-return when pred==0.
// ===========================================================================

// split weights OIHW fp32 -> [co][e][ci] bf16 hi + lo
__global__ __launch_bounds__(256) void wsplit_kernel(
    const float* __restrict__ w,
    unsigned short* __restrict__ hi, unsigned short* __restrict__ lo,
    int Cin, int total)
{
    int t = blockIdx.x * 256 + threadIdx.x;
    if (t >= total) return;
    int nine_cin = 9 * Cin;
    int co = t / nine_cin;
    int r = t - co * nine_cin;
    int e = r / Cin;
    int ci = r - e * Cin;
    float v = w[(size_t)co * nine_cin + ci * 9 + e];
    unsigned short h = f2bf(v);
    hi[t] = h;
    lo[t] = f2bf(v - bf2f(h));
}

// x all batches: NCHW fp32 -> NHWC bf16 hi + lo (gated)
__global__ __launch_bounds__(256) void xsplitb_kernel(
    const float* __restrict__ x, const int* __restrict__ predp,
    unsigned short* __restrict__ hi, unsigned short* __restrict__ lo)
{
    if (__builtin_amdgcn_readfirstlane(*predp) == 0) return;
    int p = blockIdx.x * 256 + threadIdx.x;
    if (p >= BB * HWSZ) return;
    int b = p / HWSZ, n = p % HWSZ;
    const float* sp = x + (size_t)b * 32 * HWSZ + n;
    unsigned short uh[32], ul[32];
#pragma unroll
    for (int c = 0; c < 32; ++c) {
        float v = sp[(size_t)c * HWSZ];
        unsigned short h = f2bf(v);
        uh[c] = h;
        ul[c] = f2bf(v - bf2f(h));
    }
    uint4* dh = (uint4*)(hi + (size_t)p * 32);
    uint4* dl = (uint4*)(lo + (size_t)p * 32);
#pragma unroll
    for (int g = 0; g < 4; ++g) {
        uint4 vh, vl;
        vh.x = (unsigned)uh[g*8+0] | ((unsigned)uh[g*8+1] << 16);
        vh.y = (unsigned)uh[g*8+2] | ((unsigned)uh[g*8+3] << 16);
        vh.z = (unsigned)uh[g*8+4] | ((unsigned)uh[g*8+5] << 16);
        vh.w = (unsigned)uh[g*8+6] | ((unsigned)uh[g*8+7] << 16);
        vl.x = (unsigned)ul[g*8+0] | ((unsigned)ul[g*8+1] << 16);
        vl.y = (unsigned)ul[g*8+2] | ((unsigned)ul[g*8+3] << 16);
        vl.z = (unsigned)ul[g*8+4] | ((unsigned)ul[g*8+5] << 16);
        vl.w = (unsigned)ul[g*8+6] | ((unsigned)ul[g*8+7] << 16);
        dh[g] = vh;
        dl[g] = vl;
    }
}

// branch 3x3 conv, pad=1, bias+ReLU, hi/lo bf16 in, 3-MFMA per tap-chunk.
// OUTMODE 0: write bf16 hi/lo NHWC (t1). OUTMODE 1: write fp32 NCHW (xb).
template<int CIN, int COUT, int OUTMODE>
__global__ __launch_bounds__(256) void bconv_kernel(
    const unsigned short* __restrict__ in_hi, const unsigned short* __restrict__ in_lo,
    const unsigned short* __restrict__ wAh, const unsigned short* __restrict__ wAl,
    const unsigned short* __restrict__ wBh, const unsigned short* __restrict__ wBl,
    const float* __restrict__ bA, const float* __restrict__ bB,
    const int* __restrict__ predp,
    unsigned short* __restrict__ out_hi, unsigned short* __restrict__ out_lo,
    float* __restrict__ out_f32)
{
    const int p = __builtin_amdgcn_readfirstlane(*predp);
    if (p == 0) return;
    const unsigned short* whi = (p == 1) ? wAh : wBh;
    const unsigned short* wlo = (p == 1) ? wAl : wBl;
    const float* bias = (p == 1) ? bA : bB;

    constexpr int NPG = (COUT == 64) ? 4 : 2;
    __shared__ unsigned short s_hi[198 * LPAD];
    __shared__ unsigned short s_lo[198 * LPAD];

    const int tid  = threadIdx.x;
    const int lane = tid & 63;
    const int wave = tid >> 6;
    const int nl   = lane & 15;
    const int quad = lane >> 4;
    const int row  = blockIdx.x / 6;
    const int x0   = (blockIdx.x % 6) * 64;
    const int b    = blockIdx.y;
    const int co_w0 = (COUT == 64) ? wave * 16 : (wave & 1) * 16;
    const int pg0   = (COUT == 64) ? 0 : (wave >> 1) * 2;

    f32x4 acc[NPG];
#pragma unroll
    for (int g = 0; g < NPG; ++g) acc[g] = (f32x4){0.f,0.f,0.f,0.f};

    const unsigned short* ibh = in_hi + (size_t)b * HWSZ * CIN;
    const unsigned short* ibl = in_lo + (size_t)b * HWSZ * CIN;

#pragma unroll
    for (int ci0 = 0; ci0 < CIN; ci0 += 32) {
        __syncthreads();
        for (int idx = tid; idx < 792; idx += 256) {
            int qs   = idx & 3;
            int cell = idx >> 2;
            int px   = cell % 66;
            int r    = cell / 66;
            int gy   = row + r - 1;
            int gx   = x0 + px - 1;
            uint4 vh = {0u,0u,0u,0u}, vl = {0u,0u,0u,0u};
            if ((unsigned)gy < (unsigned)HH && (unsigned)gx < (unsigned)WW) {
                size_t base = (size_t)(gy * WW + gx) * CIN + ci0 + qs * 8;
                vh = *(const uint4*)(ibh + base);
                vl = *(const uint4*)(ibl + base);
            }
            *(uint4*)(s_hi + cell * LPAD + qs * 8) = vh;
            *(uint4*)(s_lo + cell * LPAD + qs * 8) = vl;
        }
        __syncthreads();
#pragma unroll
        for (int e = 0; e < 9; ++e) {
            const int er = e / 3, ec = e % 3;
            size_t woff = (size_t)(co_w0 + nl) * (9 * CIN) + e * CIN + ci0 + quad * 8;
            short8 ah = *(const short8*)(whi + woff);
            short8 al = *(const short8*)(wlo + woff);
#pragma unroll
            for (int g = 0; g < NPG; ++g) {
                int cell = er * 66 + (pg0 + g) * 16 + nl + ec;
                short8 bh = *(const short8*)(s_hi + cell * LPAD + quad * 8);
                short8 bl = *(const short8*)(s_lo + cell * LPAD + quad * 8);
                acc[g] = __builtin_amdgcn_mfma_f32_16x16x32_bf16(ah, bh, acc[g], 0, 0, 0);
                acc[g] = __builtin_amdgcn_mfma_f32_16x16x32_bf16(ah, bl, acc[g], 0, 0, 0);
                acc[g] = __builtin_amdgcn_mfma_f32_16x16x32_bf16(al, bh, acc[g], 0, 0, 0);
            }
        }
    }

    const int cb = co_w0 + quad * 4;
#pragma unroll
    for (int g = 0; g < NPG; ++g) {
        int px = x0 + (pg0 + g) * 16 + nl;
        float r0 = fmaxf(acc[g][0] + bias[cb + 0], 0.f);
        float r1 = fmaxf(acc[g][1] + bias[cb + 1], 0.f);
        float r2 = fmaxf(acc[g][2] + bias[cb + 2], 0.f);
        float r3 = fmaxf(acc[g][3] + bias[cb + 3], 0.f);
        if (OUTMODE == 0) {
            size_t base = ((size_t)b * HWSZ + row * WW + px) * COUT + cb;
            ushort4 vh, vl;
            unsigned short h;
            h = f2bf(r0); vh.x = h; vl.x = f2bf(r0 - bf2f(h));
            h = f2bf(r1); vh.y = h; vl.y = f2bf(r1 - bf2f(h));
            h = f2bf(r2); vh.z = h; vl.z = f2bf(r2 - bf2f(h));
            h = f2bf(r3); vh.w = h; vl.w = f2bf(r3 - bf2f(h));
            *(ushort4*)(out_hi + base) = vh;
            *(ushort4*)(out_lo + base) = vl;
        } else {
            size_t sp = (size_t)row * WW + px;
            out_f32[((size_t)b * COUT + cb + 0) * HWSZ + sp] = r0;
            out_f32[((size_t)b * COUT + cb + 1) * HWSZ + sp] = r1;
            out_f32[((size_t)b * COUT + cb + 2) * HWSZ + sp] = r2;
            out_f32[((size_t)b * COUT + cb + 3) * HWSZ + sp] = r3;
        }
    }
}

// ===========================================================================
// NUMERIC CHAIN — fp32
// ===========================================================================
__global__ __launch_bounds__(256) void lnpw_kernel(
    const float* __restrict__ x, const float* __restrict__ xb,
    const int* __restrict__ predp,
    const float* __restrict__ lnw, const float* __restrict__ lnb,
    const float* __restrict__ pww,
    float* __restrict__ qkvp)
{
    int p = blockIdx.x * 256 + threadIdx.x;
    if (p >= BB * HWSZ) return;
    int pr = __builtin_amdgcn_readfirstlane(*predp);
    const float* src = (pr == 0) ? x : xb;
    int b = p / HWSZ, n = p % HWSZ;
    const float* sp = src + (size_t)b * 32 * HWSZ + n;
    float v[32];
    float mean = 0.f;
#pragma unroll
    for (int c = 0; c < 32; ++c) { v[c] = sp[(size_t)c * HWSZ]; mean += v[c]; }
    mean *= (1.f / 32.f);
    float var = 0.f;
#pragma unroll
    for (int c = 0; c < 32; ++c) { float d = v[c] - mean; var += d * d; }
    var *= (1.f / 32.f);
    float rstd = rsqrtf(var + 1e-6f);
#pragma unroll
    for (int c = 0; c < 32; ++c)
        v[c] = (v[c] - mean) * rstd * lnw[c] + lnb[c];

    float acc[96];
#pragma unroll
    for (int co = 0; co < 96; ++co) acc[co] = 0.f;
    for (int ci = 0; ci < 32; ++ci) {
        float va = v[ci];
#pragma unroll
        for (int co = 0; co < 96; ++co)
            acc[co] = fmaf(pww[co * 32 + ci], va, acc[co]);
    }
    float* op = qkvp + (size_t)b * 96 * HWSZ + n;
#pragma unroll
    for (int co = 0; co < 96; ++co) op[(size_t)co * HWSZ] = acc[co];
}

// q/k depthwise-conv-on-the-fly + attention stats — LDS-staged.
// Per-thread ILP variants (R1/R3/R4) all stalled at 250-600us with VALUBusy
// 5-7%: a wave only keeps ~2-4 stencil loads in flight regardless of source
// form. This version stages cooperatively: block = 4 output rows x 384 cols
// of one (b,h); 6 input rows x 4 channels into LDS via 9 independent
// coalesced f32x4 loads per thread (9KB in flight per wave), stencil served
// from LDS at lane-stride-1 (bank-conflict-free). Two phases: q then k
// (LDS reused), stats fused, cross-wave LDS reduction -> 1 atomic set/block.
// LDS tile layout: [ch][row][392]; data col c at index c+4 (16B-aligned f32x4
// stores); zero halo at index 3 and 388.
__global__ __launch_bounds__(256) void qkdwstats_kernel(
    const float* __restrict__ qkvp, const float* __restrict__ dww,
    float* __restrict__ stats)
{
    __shared__ float s_t[4][6][392];
    __shared__ float red[4][24];

    const int bh = blockIdx.y;
    const int b = bh >> 3, h = bh & 7;
    const float* qbase = qkvp + ((size_t)b * 96 + h * 4) * HWSZ;
    const float* kbase = qkvp + ((size_t)b * 96 + 32 + h * 4) * HWSZ;
    const float* wq = dww + (h * 4) * 9;
    const float* wk = dww + (32 + h * 4) * 9;

    const int tid  = threadIdx.x;
    const int w    = tid >> 6;      // wave -> output row y0+w
    const int lane = tid & 63;
    const int y0   = blockIdx.x * 4;

    // zero halo cells (cols 3 and 388 of every [ch][row]); persist both phases
    if (tid < 48) {
        int ch = tid / 12, rem = tid % 12;
        int r = rem >> 1, side = rem & 1;
        s_t[ch][r][side ? 388 : 3] = 0.f;
    }

    float s[16], qn[4], kn[4];
#pragma unroll
    for (int i = 0; i < 16; ++i) s[i] = 0.f;
#pragma unroll
    for (int i = 0; i < 4; ++i) { qn[i] = 0.f; kn[i] = 0.f; }

    // ---- phase 1: stage q channels ----
    {
#pragma unroll
        for (int i = 0; i < 9; ++i) {
            int idx = i * 256 + tid;            // [0, 2304)
            int ch  = idx / 576;
            int rem = idx - ch * 576;
            int r   = rem / 96;
            int g   = rem - r * 96;
            int gy  = y0 + r - 1;
            f32x4 v = {0.f, 0.f, 0.f, 0.f};
            if ((unsigned)gy < (unsigned)HH)
                v = *(const f32x4*)(qbase + (size_t)ch * HWSZ + (size_t)gy * WW + g * 4);
            *(f32x4*)&s_t[ch][r][g * 4 + 4] = v;   // 16B-aligned
        }
    }
    __syncthreads();

    // ---- compute q convs: q[ch][jj] for px col = jj*64+lane of row y0+w ----
    float q[4][6];
#pragma unroll
    for (int ch = 0; ch < 4; ++ch) {
        const float* w9 = wq + ch * 9;
#pragma unroll
        for (int jj = 0; jj < 6; ++jj) {
            int colL = jj * 64 + lane + 4;
            float acc = 0.f;
#pragma unroll
            for (int dy = 0; dy < 3; ++dy) {
                const float* rr = &s_t[ch][w + dy][0];
                acc = fmaf(rr[colL - 1], w9[dy * 3 + 0], acc);
                acc = fmaf(rr[colL    ], w9[dy * 3 + 1], acc);
                acc = fmaf(rr[colL + 1], w9[dy * 3 + 2], acc);
            }
            q[ch][jj] = acc;
            qn[ch] = fmaf(acc, acc, qn[ch]);
        }
    }
    __syncthreads();

    // ---- phase 2: stage k channels (reuse LDS) ----
    {
#pragma unroll
        for (int i = 0; i < 9; ++i) {
            int idx = i * 256 + tid;
            int ch  = idx / 576;
            int rem = idx - ch * 576;
            int r   = rem / 96;
            int g   = rem - r * 96;
            int gy  = y0 + r - 1;
            f32x4 v = {0.f, 0.f, 0.f, 0.f};
            if ((unsigned)gy < (unsigned)HH)
                v = *(const f32x4*)(kbase + (size_t)ch * HWSZ + (size_t)gy * WW + g * 4);
            *(f32x4*)&s_t[ch][r][g * 4 + 4] = v;
        }
    }
    __syncthreads();

    // ---- compute k convs, fuse stats ----
#pragma unroll
    for (int d = 0; d < 4; ++d) {
        const float* w9 = wk + d * 9;
#pragma unroll
        for (int jj = 0; jj < 6; ++jj) {
            int colL = jj * 64 + lane + 4;
            float kv = 0.f;
#pragma unroll
            for (int dy = 0; dy < 3; ++dy) {
                const float* rr = &s_t[d][w + dy][0];
                kv = fmaf(rr[colL - 1], w9[dy * 3 + 0], kv);
                kv = fmaf(rr[colL    ], w9[dy * 3 + 1], kv);
                kv = fmaf(rr[colL + 1], w9[dy * 3 + 2], kv);
            }
            kn[d] = fmaf(kv, kv, kn[d]);
#pragma unroll
            for (int c = 0; c < 4; ++c)
                s[c * 4 + d] = fmaf(q[c][jj], kv, s[c * 4 + d]);
        }
    }

    // ---- reduction: wave shuffle -> cross-wave LDS -> 1 atomic set/block ----
#pragma unroll
    for (int i = 0; i < 16; ++i) {
        float v = waveSum(s[i]);
        if (lane == 0) red[w][i] = v;
    }
#pragma unroll
    for (int i = 0; i < 4; ++i) {
        float v = waveSum(qn[i]);
        if (lane == 0) red[w][16 + i] = v;
        float u = waveSum(kn[i]);
        if (lane == 0) red[w][20 + i] = u;
    }
    __syncthreads();
    if (tid < 24) {
        float v = red[0][tid] + red[1][tid] + red[2][tid] + red[3][tid];
        atomicAdd(&stats[bh * 24 + tid], v);
    }
}

// v depthwise conv into q-channel slots. 8 px/thread (R1-proven form).
__global__ __launch_bounds__(256) void vdw_kernel(
    float* __restrict__ qkvp, const float* __restrict__ dww)
{
    int t = blockIdx.x * 256 + threadIdx.x;     // [0, 2359296)
    int bc = t / 18432;
    int g  = t - bc * 18432;
    int b = bc >> 5, c = bc & 31;
    int y  = g / 48;
    int xg = (g - y * 48) * 8;
    const float* ip = qkvp + ((size_t)b * 96 + 64 + c) * HWSZ;
    const float* wc = dww + (64 + c) * 9;
    float o[8];
    dwconv8(ip, wc, y, xg, o);
    float* op = qkvp + ((size_t)b * 96 + c) * HWSZ + (size_t)y * WW + xg;
    f32x4 v0 = {o[0], o[1], o[2], o[3]};
    f32x4 v1 = {o[4], o[5], o[6], o[7]};
    *(f32x4*)op = v0;
    *(f32x4*)(op + 4) = v1;
}

__global__ void attnmb_kernel(const float* __restrict__ stats,
                              const float* __restrict__ temp,
                              const float* __restrict__ projw,
                              float* __restrict__ Mb)
{
    __shared__ float attn_s[4][8][4][4];
    int t = threadIdx.x;
    if (t < 128) {
        int b = t >> 5;
        int h = (t >> 2) & 7;
        int c = t & 3;
        const float* st = stats + (b * 8 + h) * 24;
        float qn = fmaxf(sqrtf(st[16 + c]), 1e-12f);
        float tp = temp[h];
        float raw[4];
#pragma unroll
        for (int d = 0; d < 4; ++d) {
            float kn = fmaxf(sqrtf(st[20 + d]), 1e-12f);
            raw[d] = st[c * 4 + d] / (qn * kn) * tp;
        }
        float m = fmaxf(fmaxf(raw[0], raw[1]), fmaxf(raw[2], raw[3]));
        float e0 = expf(raw[0] - m), e1 = expf(raw[1] - m);
        float e2 = expf(raw[2] - m), e3 = expf(raw[3] - m);
        float inv = 1.f / (e0 + e1 + e2 + e3);
        attn_s[b][h][c][0] = e0 * inv;
        attn_s[b][h][c][1] = e1 * inv;
        attn_s[b][h][c][2] = e2 * inv;
        attn_s[b][h][c][3] = e3 * inv;
    }
    __syncthreads();
    for (int idx = t; idx < 4096; idx += 256) {
        int b = idx >> 10;
        int r = idx & 1023;
        int co = r >> 5;
        int j = r & 31;
        int h = j >> 2;
        int d = j & 3;
        float m = 0.f;
#pragma unroll
        for (int l = 0; l < 4; ++l)
            m = fmaf(projw[co * 32 + h * 4 + l], attn_s[b][h][l][d], m);
        Mb[idx] = m;
    }
}

__global__ __launch_bounds__(256) void e1_kernel(
    float* __restrict__ qkvp, const float* __restrict__ x,
    const float* __restrict__ xb, const int* __restrict__ predp,
    const float* __restrict__ Mb, const float* __restrict__ ff1w)
{
    int p = blockIdx.x * 256 + threadIdx.x;
    if (p >= BB * HWSZ) return;
    int pr = __builtin_amdgcn_readfirstlane(*predp);
    const float* src = (pr == 0) ? x : xb;
    int b = p / HWSZ, n = p % HWSZ;
    float* vp = qkvp + (size_t)b * 96 * HWSZ + n;
    const float* Mbb = Mb + b * 1024;
    float y[32];
#pragma unroll
    for (int c = 0; c < 32; ++c) y[c] = 0.f;
    for (int j = 0; j < 32; ++j) {
        float vj = vp[(size_t)j * HWSZ];
#pragma unroll
        for (int co = 0; co < 32; ++co)
            y[co] = fmaf(Mbb[co * 32 + j], vj, y[co]);
    }
    const float* xp = src + (size_t)b * 32 * HWSZ + n;
#pragma unroll
    for (int c = 0; c < 32; ++c) y[c] += xp[(size_t)c * HWSZ];
    for (int co = 0; co < 32; ++co) {
        float s = 0.f;
#pragma unroll
        for (int ci = 0; ci < 32; ++ci)
            s = fmaf(ff1w[co * 32 + ci], y[ci], s);
        vp[(size_t)co * HWSZ] = gelu_exact(s);
    }
}

// final depthwise conv + gelu. 8 px/thread (R1-proven form).
__global__ __launch_bounds__(256) void fdw_kernel(
    const float* __restrict__ z1, const float* __restrict__ w,
    float* __restrict__ out)
{
    int t = blockIdx.x * 256 + threadIdx.x;     // [0, 2359296)
    int bc = t / 18432;
    int g  = t - bc * 18432;
    int b = bc >> 5, c = bc & 31;
    int y  = g / 48;
    int xg = (g - y * 48) * 8;
    const float* ip = z1 + ((size_t)b * 96 + c) * HWSZ;
    const float* wc = w + c * 9;
    float o[8];
    dwconv8(ip, wc, y, xg, o);
#pragma unroll
    for (int j = 0; j < 8; ++j) o[j] = gelu_exact(o[j]);
    float* op = out + ((size_t)b * 32 + c) * HWSZ + (size_t)y * WW + xg;
    f32x4 v0 = {o[0], o[1], o[2], o[3]};
    f32x4 v1 = {o[4], o[5], o[6], o[7]};
    *(f32x4*)op = v0;
    *(f32x4*)(op + 4) = v1;
}

// ---------------------------------------------------------------------------
extern "C" void kernel_launch(void* const* d_in, const int* in_sizes, int n_in,
                              void* d_out, int out_size, void* d_ws, size_t ws_size,
                              hipStream_t stream)
{
    (void)in_sizes; (void)n_in; (void)out_size; (void)ws_size;
    const float* x      = (const float*)d_in[0];
    const float* ln_w   = (const float*)d_in[1];
    const float* ln_b   = (const float*)d_in[2];
    const float* temp   = (const float*)d_in[3];
    const float* pw_w   = (const float*)d_in[4];
    const float* dw_w   = (const float*)d_in[5];
    const float* proj_w = (const float*)d_in[6];
    const float* ff1_w  = (const float*)d_in[7];
    const float* ffdw_w = (const float*)d_in[8];
    const float* det_w1 = (const float*)d_in[9];
    const float* det_b1 = (const float*)d_in[10];
    const float* det_w2 = (const float*)d_in[11];
    const float* det_b2 = (const float*)d_in[12];
    const float* det_w3 = (const float*)d_in[13];
    const float* det_b3 = (const float*)d_in[14];
    const float* fc_w   = (const float*)d_in[15];
    const float* fc_b   = (const float*)d_in[16];
    const float* hvi_w1 = (const float*)d_in[17];
    const float* hvi_b1 = (const float*)d_in[18];
    const float* hvi_w2 = (const float*)d_in[19];
    const float* hvi_b2 = (const float*)d_in[20];
    const float* ycc_w1 = (const float*)d_in[21];
    const float* ycc_b1 = (const float*)d_in[22];
    const float* ycc_w2 = (const float*)d_in[23];
    const float* ycc_b2 = (const float*)d_in[24];

    float* ws     = (float*)d_ws;
    float* misc   = ws + OFF_MISC;
    float* A      = ws + OFF_A;
    // det phase
    unsigned short* x0bf  = (unsigned short*)A;
    unsigned short* f1bf  = (unsigned short*)(A + 2359296);
    unsigned short* f2bf  = (unsigned short*)(A + 7077888);
    unsigned short* d3out = (unsigned short*)(A + 16515072);
    unsigned short* w1p   = (unsigned short*)(A + 56423104);
    unsigned short* w2p   = (unsigned short*)(A + 56432320);
    unsigned short* w3p   = (unsigned short*)(A + 56469184);
    // branch phase
    unsigned short* xs_hi = (unsigned short*)A;
    unsigned short* xs_lo = (unsigned short*)(A + 9437184);
    unsigned short* t1_hi = (unsigned short*)(A + 18874368);
    unsigned short* t1_lo = (unsigned short*)(A + 37748736);
    unsigned short* bw    = (unsigned short*)(ws + OFF_BW);
    unsigned short* bw_h1h = bw;            unsigned short* bw_h1l = bw + 18432;
    unsigned short* bw_y1h = bw + 36864;    unsigned short* bw_y1l = bw + 55296;
    unsigned short* bw_h2h = bw + 73728;    unsigned short* bw_h2l = bw + 92160;
    unsigned short* bw_y2h = bw + 110592;   unsigned short* bw_y2l = bw + 129024;
    // qkv phase
    float* qkvp   = A;
    float* xb     = (float*)d_out;
    float* pooled = misc + MISC_POOLED;
    int*   pred   = (int*)(misc + MISC_PRED);
    float* stats  = misc + MISC_STATS;
    float* Mb     = misc + MISC_MB;
    float* out    = (float*)d_out;

    hipMemsetAsync(misc, 0, 2048 * sizeof(float), stream);

    dim3 blk(256);
    // ---- weight + input conversion ----
    wcvt_kernel<<<(18432 + 255) / 256, blk, 0, stream>>>(det_w1, w1p, 32, 18432);
    wcvt_kernel<<<(73728 + 255) / 256, blk, 0, stream>>>(det_w2, w2p, 64, 73728);
    wcvt_kernel<<<(294912 + 255) / 256, blk, 0, stream>>>(det_w3, w3p, 128, 294912);
    xcvt_kernel<<<576, blk, 0, stream>>>(x, x0bf);
    wsplit_kernel<<<72, blk, 0, stream>>>(hvi_w1, bw_h1h, bw_h1l, 32, 18432);
    wsplit_kernel<<<72, blk, 0, stream>>>(ycc_w1, bw_y1h, bw_y1l, 32, 18432);
    wsplit_kernel<<<72, blk, 0, stream>>>(hvi_w2, bw_h2h, bw_h2l, 64, 18432);
    wsplit_kernel<<<72, blk, 0, stream>>>(ycc_w2, bw_y2h, bw_y2l, 64, 18432);

    // ---- detector (batch 0 only; feeds argmax) ----
    mfma_conv2_kernel<32, 64>  <<<2304, blk, 0, stream>>>(x0bf, w1p, det_b1, f1bf);
    mfma_conv2_kernel<64, 128> <<<2304, blk, 0, stream>>>(f1bf, w2p, det_b2, f2bf);
    mfma_conv2_kernel<128, 256><<<2304, blk, 0, stream>>>(f2bf, w3p, det_b3, d3out);
    pool_kernel<<<64, blk, 0, stream>>>(d3out, pooled);
    fc_argmax_kernel<<<1, 256, 0, stream>>>(pooled, fc_w, fc_b, pred);

    // ---- gated color-space branch (bf16 hi/lo 3-MFMA; ~fp32 accuracy) ----
    xsplitb_kernel<<<2304, blk, 0, stream>>>(x, pred, xs_hi, xs_lo);
    bconv_kernel<32, 64, 0><<<dim3(2304, BB), blk, 0, stream>>>(
        xs_hi, xs_lo, bw_h1h, bw_h1l, bw_y1h, bw_y1l, hvi_b1, ycc_b1, pred,
        t1_hi, t1_lo, nullptr);
    bconv_kernel<64, 32, 1><<<dim3(2304, BB), blk, 0, stream>>>(
        t1_hi, t1_lo, bw_h2h, bw_h2l, bw_y2h, bw_y2l, hvi_b2, ycc_b2, pred,
        nullptr, nullptr, xb);

    // ---- fused LN + pw(1x1) -> qkvp ----
    lnpw_kernel<<<2304, blk, 0, stream>>>(x, xb, pred, ln_w, ln_b, pw_w, qkvp);

    // ---- q/k dw-on-the-fly + stats; v dw into q-channel slots ----
    qkdwstats_kernel<<<dim3(96, 32), blk, 0, stream>>>(qkvp, dw_w, stats);
    vdw_kernel<<<9216, blk, 0, stream>>>(qkvp, dw_w);
    attnmb_kernel<<<1, 256, 0, stream>>>(stats, temp, proj_w, Mb);

    // ---- epilogue ----
    e1_kernel<<<2304, blk, 0, stream>>>(qkvp, x, xb, pred, Mb, ff1_w);
    fdw_kernel<<<9216, blk, 0, stream>>>(qkvp, ffdw_w, out);
}

// Round 6
// 1226.104 us; speedup vs baseline: 1.4178x; 1.0104x over previous
//
#include <hip/hip_runtime.h>
#include <hip/hip_bf16.h>
#include <math.h>

#define HH 384
#define WW 384
#define HWSZ (HH*WW)   // 147456
#define BB 4

typedef __attribute__((ext_vector_type(8))) short short8;
typedef __attribute__((ext_vector_type(4))) float f32x4;

// ---- workspace layout (float offsets). TOTAL: 16384 + 56,623,104 + 73,728
// = 56,713,216 fl = 226.9 MB (226.6 proved OK in r2-r4).
static const size_t OFF_MISC = 0;        // 16384 floats
static const size_t OFF_A    = 16384;    // big region, 56,623,104 floats
static const size_t OFF_BW   = OFF_A + 56623104;   // 73,728 fl branch weights
// region-A sequenced reuse (float offsets within A):
//   det phase:  x0 bf16   @0          ; f1 bf16 @2,359,296 ; f2 bf16 @7,077,888
//               d3out bf16@16,515,072 (ends 35,389,440)
//               det W' bf16 @56,423,104 (ends 56,616,640)
//   branch:     xs_hi @0 (9.44M fl) ; xs_lo @9.44M ; t1_hi @18.87M ; t1_lo @37.75M
//               (t1_lo overwrites det W' - dead by then; xb lives in d_out)
//   qkv:        qkvp fp32 @0 (56,623,104 fl)
// misc (float offsets):
static const size_t MISC_POOLED = 0;     // 256 floats
static const size_t MISC_PRED   = 1024;  // 1 int
static const size_t MISC_STATS  = 1056;  // 768 floats
static const size_t MISC_MB     = 2048;  // 4096 floats

#define LPAD 40   // LDS row stride in ushorts: (cell*80+quad*16)/4 %32 covers
                  // all 32 banks 2-way (free) vs stride 32's 8-way conflict.

__device__ __forceinline__ float waveSum(float v) {
#pragma unroll
    for (int off = 32; off > 0; off >>= 1) v += __shfl_down(v, off);
    return v;
}

__device__ __forceinline__ float gelu_exact(float v) {
    return 0.5f * v * (1.0f + erff(v * 0.70710678118654752f));
}

__device__ __forceinline__ unsigned short f2bf(float f) {
    __hip_bfloat16 h = __float2bfloat16(f);
    return *(unsigned short*)&h;
}
__device__ __forceinline__ float bf2f(unsigned short u) {
    unsigned int b = ((unsigned int)u) << 16;
    return __uint_as_float(b);
}

// 3x3 depthwise conv, zero-pad, 8 consecutive pixels of row y at column xg
// (xg multiple of 8). Proven no-spill form (R1: 48 VGPR, WRITE_SIZE clean).
__device__ __forceinline__ void dwconv8(const float* __restrict__ base,
                                        const float* __restrict__ w9,
                                        int y, int xg, float o[8])
{
#pragma unroll
    for (int j = 0; j < 8; ++j) o[j] = 0.f;
#pragma unroll
    for (int dy = 0; dy < 3; ++dy) {
        int gy = y + dy - 1;
        if ((unsigned)gy >= (unsigned)HH) continue;
        const float* rp = base + (size_t)gy * WW + xg;
        f32x4 m0 = *(const f32x4*)(rp);
        f32x4 m1 = *(const f32x4*)(rp + 4);
        float r0 = (xg > 0) ? rp[-1] : 0.f;
        float r9 = (xg + 8 < WW) ? rp[8] : 0.f;
        float r[10] = {r0, m0[0], m0[1], m0[2], m0[3],
                           m1[0], m1[1], m1[2], m1[3], r9};
        float w0 = w9[dy * 3 + 0], w1 = w9[dy * 3 + 1], w2 = w9[dy * 3 + 2];
#pragma unroll
        for (int j = 0; j < 8; ++j)
            o[j] = fmaf(r[j], w0, fmaf(r[j + 1], w1, fmaf(r[j + 2], w2, o[j])));
    }
}

// ===========================================================================
// DETECTOR PATH (bf16 MFMA) — only argmax(logits[0]) is consumed.
// ===========================================================================

// x batch0: NCHW fp32 -> NHWC bf16
__global__ __launch_bounds__(256) void xcvt_kernel(
    const float* __restrict__ x, unsigned short* __restrict__ x0)
{
    int px = blockIdx.x * 256 + threadIdx.x;
    if (px >= HWSZ) return;
    unsigned short u[32];
#pragma unroll
    for (int c = 0; c < 32; ++c) u[c] = f2bf(x[(size_t)c * HWSZ + px]);
    uint4* dst = (uint4*)(x0 + (size_t)px * 32);
#pragma unroll
    for (int g = 0; g < 4; ++g) {
        uint4 v;
        v.x = (unsigned)u[g*8+0] | ((unsigned)u[g*8+1] << 16);
        v.y = (unsigned)u[g*8+2] | ((unsigned)u[g*8+3] << 16);
        v.z = (unsigned)u[g*8+4] | ((unsigned)u[g*8+5] << 16);
        v.w = (unsigned)u[g*8+6] | ((unsigned)u[g*8+7] << 16);
        dst[g] = v;
    }
}

// weights OIHW fp32 -> [co][e=dy*3+dx][ci] bf16
__global__ __launch_bounds__(256) void wcvt_kernel(
    const float* __restrict__ w, unsigned short* __restrict__ wp,
    int Cin, int total)
{
    int t = blockIdx.x * 256 + threadIdx.x;
    if (t >= total) return;
    int nine_cin = 9 * Cin;
    int co = t / nine_cin;
    int r = t - co * nine_cin;
    int e = r / Cin;
    int ci = r - e * Cin;
    wp[t] = f2bf(w[(size_t)co * nine_cin + ci * 9 + e]);
}

// implicit-GEMM 3x3 conv, pad=1, bias+ReLU, NHWC bf16 (detector).
template<int CIN, int COUT>
__global__ __launch_bounds__(256) void mfma_conv2_kernel(
    const unsigned short* __restrict__ in,
    const unsigned short* __restrict__ wp,
    const float* __restrict__ bias,
    unsigned short* __restrict__ out)
{
    constexpr int NT = COUT / 64;
    __shared__ unsigned short s_in[198 * LPAD];

    const int tid  = threadIdx.x;
    const int lane = tid & 63;
    const int wave = tid >> 6;
    const int nl   = lane & 15;
    const int quad = lane >> 4;
    const int row  = blockIdx.x / 6;
    const int x0   = (blockIdx.x % 6) * 64;
    const int co_w0 = wave * (COUT / 4);

    f32x4 acc[4][NT];
#pragma unroll
    for (int pg = 0; pg < 4; ++pg)
#pragma unroll
        for (int ct = 0; ct < NT; ++ct) acc[pg][ct] = (f32x4){0.f,0.f,0.f,0.f};

#pragma unroll
    for (int ci0 = 0; ci0 < CIN; ci0 += 32) {
        __syncthreads();
        for (int idx = tid; idx < 792; idx += 256) {
            int qs   = idx & 3;
            int cell = idx >> 2;
            int px   = cell % 66;
            int r    = cell / 66;
            int gy   = row + r - 1;
            int gx   = x0 + px - 1;
            uint4 v = {0u,0u,0u,0u};
            if ((unsigned)gy < (unsigned)HH && (unsigned)gx < (unsigned)WW)
                v = *(const uint4*)(in + (size_t)(gy * WW + gx) * CIN + ci0 + qs * 8);
            *(uint4*)(s_in + cell * LPAD + qs * 8) = v;
        }
        __syncthreads();
#pragma unroll
        for (int e = 0; e < 9; ++e) {
            const int er = e / 3, ec = e % 3;
            short8 bfrag[4];
#pragma unroll
            for (int pg = 0; pg < 4; ++pg)
                bfrag[pg] = *(const short8*)(s_in + ((er * 66 + pg * 16 + nl + ec) * LPAD + quad * 8));
#pragma unroll
            for (int ct = 0; ct < NT; ++ct) {
                short8 afrag = *(const short8*)(wp
                    + (size_t)(co_w0 + ct * 16 + nl) * (9 * CIN) + e * CIN + ci0 + quad * 8);
#pragma unroll
                for (int pg = 0; pg < 4; ++pg)
                    acc[pg][ct] = __builtin_amdgcn_mfma_f32_16x16x32_bf16(afrag, bfrag[pg], acc[pg][ct], 0, 0, 0);
            }
        }
    }

#pragma unroll
    for (int pg = 0; pg < 4; ++pg) {
        int px = x0 + pg * 16 + nl;
        unsigned short* op = out + ((size_t)row * WW + px) * COUT;
#pragma unroll
        for (int ct = 0; ct < NT; ++ct) {
            int cb = co_w0 + ct * 16 + quad * 4;
            ushort4 v;
            v.x = f2bf(fmaxf(acc[pg][ct][0] + bias[cb + 0], 0.f));
            v.y = f2bf(fmaxf(acc[pg][ct][1] + bias[cb + 1], 0.f));
            v.z = f2bf(fmaxf(acc[pg][ct][2] + bias[cb + 2], 0.f));
            v.w = f2bf(fmaxf(acc[pg][ct][3] + bias[cb + 3], 0.f));
            *(ushort4*)(op + cb) = v;
        }
    }
}

// global-average-pool sums over det3 output [HW][256] bf16 -> pooled[256]
__global__ __launch_bounds__(256) void pool_kernel(
    const unsigned short* __restrict__ d3, float* __restrict__ pooled)
{
    __shared__ float s_pool[256];
    int t = threadIdx.x;
    s_pool[t] = 0.f;
    __syncthreads();
    int co8 = (t & 31) * 8;
    int pxg = t >> 5;
    float sums[8];
#pragma unroll
    for (int j = 0; j < 8; ++j) sums[j] = 0.f;
    int base = blockIdx.x * 2304 + pxg;
    for (int i = 0; i < 288; ++i) {
        int px = base + i * 8;
        const uint4* p = (const uint4*)(d3 + (size_t)px * 256 + co8);
        uint4 v = *p;
        unsigned int w[4] = {v.x, v.y, v.z, v.w};
#pragma unroll
        for (int g = 0; g < 4; ++g) {
            sums[g*2+0] += bf2f((unsigned short)(w[g] & 0xFFFF));
            sums[g*2+1] += bf2f((unsigned short)(w[g] >> 16));
        }
    }
#pragma unroll
    for (int j = 0; j < 8; ++j) atomicAdd(&s_pool[co8 + j], sums[j]);
    __syncthreads();
    atomicAdd(&pooled[t], s_pool[t]);
}

__global__ void fc_argmax_kernel(const float* __restrict__ pooled,
                                 const float* __restrict__ fcw,
                                 const float* __restrict__ fcb,
                                 int* __restrict__ pred)
{
    int t = threadIdx.x;
    float m = pooled[t] * (1.0f / (float)HWSZ);
    float p0 = m * fcw[t];
    float p1 = m * fcw[256 + t];
    float p2 = m * fcw[512 + t];
    p0 = waveSum(p0); p1 = waveSum(p1); p2 = waveSum(p2);
    __shared__ float rr[3][4];
    int wid = t >> 6, lane = t & 63;
    if (lane == 0) { rr[0][wid] = p0; rr[1][wid] = p1; rr[2][wid] = p2; }
    __syncthreads();
    if (t == 0) {
        float l0 = rr[0][0] + rr[0][1] + rr[0][2] + rr[0][3] + fcb[0];
        float l1 = rr[1][0] + rr[1][1] + rr[1][2] + rr[1][3] + fcb[1];
        float l2 = rr[2][0] + rr[2][1] + rr[2][2] + rr[2][3] + fcb[2];
        int best = 0; float bv = l0;
        if (l1 > bv) { best = 1; bv = l1; }
        if (l2 > bv) { best = 2; bv = l2; }
        *pred = best;
    }
}

// ===========================================================================
// BRANCH convs — bf16 hi/lo 3-MFMA emulation (~fp19 per product; error ~1e-5).
// Gated: early-return when pred==0.
// ===========================================================================

// split weights OIHW fp32 -> [co][e][ci] bf16 hi + lo
__global__ __launch_bounds__(256) void wsplit_kernel(
    const float* __restrict__ w,
    unsigned short* __restrict__ hi, unsigned short* __restrict__ lo,
    int Cin, int total)
{
    int t = blockIdx.x * 256 + threadIdx.x;
    if (t >= total) return;
    int nine_cin = 9 * Cin;
    int co = t / nine_cin;
    int r = t - co * nine_cin;
    int e = r / Cin;
    int ci = r - e * Cin;
    float v = w[(size_t)co * nine_cin + ci * 9 + e];
    unsigned short h = f2bf(v);
    hi[t] = h;
    lo[t] = f2bf(v - bf2f(h));
}

// x all batches: NCHW fp32 -> NHWC bf16 hi + lo (gated)
__global__ __launch_bounds__(256) void xsplitb_kernel(
    const float* __restrict__ x, const int* __restrict__ predp,
    unsigned short* __restrict__ hi, unsigned short* __restrict__ lo)
{
    if (__builtin_amdgcn_readfirstlane(*predp) == 0) return;
    int p = blockIdx.x * 256 + threadIdx.x;
    if (p >= BB * HWSZ) return;
    int b = p / HWSZ, n = p % HWSZ;
    const float* sp = x + (size_t)b * 32 * HWSZ + n;
    unsigned short uh[32], ul[32];
#pragma unroll
    for (int c = 0; c < 32; ++c) {
        float v = sp[(size_t)c * HWSZ];
        unsigned short h = f2bf(v);
        uh[c] = h;
        ul[c] = f2bf(v - bf2f(h));
    }
    uint4* dh = (uint4*)(hi + (size_t)p * 32);
    uint4* dl = (uint4*)(lo + (size_t)p * 32);
#pragma unroll
    for (int g = 0; g < 4; ++g) {
        uint4 vh, vl;
        vh.x = (unsigned)uh[g*8+0] | ((unsigned)uh[g*8+1] << 16);
        vh.y = (unsigned)uh[g*8+2] | ((unsigned)uh[g*8+3] << 16);
        vh.z = (unsigned)uh[g*8+4] | ((unsigned)uh[g*8+5] << 16);
        vh.w = (unsigned)uh[g*8+6] | ((unsigned)uh[g*8+7] << 16);
        vl.x = (unsigned)ul[g*8+0] | ((unsigned)ul[g*8+1] << 16);
        vl.y = (unsigned)ul[g*8+2] | ((unsigned)ul[g*8+3] << 16);
        vl.z = (unsigned)ul[g*8+4] | ((unsigned)ul[g*8+5] << 16);
        vl.w = (unsigned)ul[g*8+6] | ((unsigned)ul[g*8+7] << 16);
        dh[g] = vh;
        dl[g] = vl;
    }
}

// branch 3x3 conv, pad=1, bias+ReLU, hi/lo bf16 in, 3-MFMA per tap-chunk.
// 4-ROW TILE version: each block covers 4 output rows x 64 cols; wave w owns
// row y0+w across ALL COUT channels (acc = 4pg x COUT/16 tiles). Staging
// brings 6 input rows: vertical halo amplification 1.5x instead of the old
// 1-row structure's 3x (R5 counters: FETCH 448MB vs 151MB ideal = the whole
// 201us). LDS 2x31.7KB = 63.4KB -> 2 blocks/CU (streaming kernel, OK).
// OUTMODE 0: write bf16 hi/lo NHWC (t1). OUTMODE 1: write fp32 NCHW (xb).
template<int CIN, int COUT, int OUTMODE>
__global__ __launch_bounds__(256) void bconv_kernel(
    const unsigned short* __restrict__ in_hi, const unsigned short* __restrict__ in_lo,
    const unsigned short* __restrict__ wAh, const unsigned short* __restrict__ wAl,
    const unsigned short* __restrict__ wBh, const unsigned short* __restrict__ wBl,
    const float* __restrict__ bA, const float* __restrict__ bB,
    const int* __restrict__ predp,
    unsigned short* __restrict__ out_hi, unsigned short* __restrict__ out_lo,
    float* __restrict__ out_f32)
{
    const int p = __builtin_amdgcn_readfirstlane(*predp);
    if (p == 0) return;
    const unsigned short* whi = (p == 1) ? wAh : wBh;
    const unsigned short* wlo = (p == 1) ? wAl : wBl;
    const float* bias = (p == 1) ? bA : bB;

    constexpr int NCT = COUT / 16;          // co-tiles per wave (4 or 2)
    __shared__ unsigned short s_hi[396 * LPAD];   // 6 rows x 66 px
    __shared__ unsigned short s_lo[396 * LPAD];

    const int tid  = threadIdx.x;
    const int lane = tid & 63;
    const int wave = tid >> 6;              // = output row within tile
    const int nl   = lane & 15;
    const int quad = lane >> 4;
    const int y0   = (blockIdx.x / 6) * 4;
    const int x0   = (blockIdx.x % 6) * 64;
    const int b    = blockIdx.y;

    f32x4 acc[4][NCT];
#pragma unroll
    for (int pg = 0; pg < 4; ++pg)
#pragma unroll
        for (int ct = 0; ct < NCT; ++ct) acc[pg][ct] = (f32x4){0.f,0.f,0.f,0.f};

    const unsigned short* ibh = in_hi + (size_t)b * HWSZ * CIN;
    const unsigned short* ibl = in_lo + (size_t)b * HWSZ * CIN;

#pragma unroll
    for (int ci0 = 0; ci0 < CIN; ci0 += 32) {
        __syncthreads();
        for (int idx = tid; idx < 1584; idx += 256) {   // 6*66 cells x 4 quads
            int qs   = idx & 3;
            int cell = idx >> 2;
            int px   = cell % 66;
            int r    = cell / 66;
            int gy   = y0 + r - 1;
            int gx   = x0 + px - 1;
            uint4 vh = {0u,0u,0u,0u}, vl = {0u,0u,0u,0u};
            if ((unsigned)gy < (unsigned)HH && (unsigned)gx < (unsigned)WW) {
                size_t base = (size_t)(gy * WW + gx) * CIN + ci0 + qs * 8;
                vh = *(const uint4*)(ibh + base);
                vl = *(const uint4*)(ibl + base);
            }
            *(uint4*)(s_hi + cell * LPAD + qs * 8) = vh;
            *(uint4*)(s_lo + cell * LPAD + qs * 8) = vl;
        }
        __syncthreads();
#pragma unroll
        for (int e = 0; e < 9; ++e) {
            const int er = e / 3, ec = e % 3;
            short8 bh[4], bl[4];
#pragma unroll
            for (int pg = 0; pg < 4; ++pg) {
                int cell = (wave + er) * 66 + pg * 16 + nl + ec;
                bh[pg] = *(const short8*)(s_hi + cell * LPAD + quad * 8);
                bl[pg] = *(const short8*)(s_lo + cell * LPAD + quad * 8);
            }
#pragma unroll
            for (int ct = 0; ct < NCT; ++ct) {
                size_t woff = (size_t)(ct * 16 + nl) * (9 * CIN) + e * CIN + ci0 + quad * 8;
                short8 ah = *(const short8*)(whi + woff);
                short8 al = *(const short8*)(wlo + woff);
#pragma unroll
                for (int pg = 0; pg < 4; ++pg) {
                    acc[pg][ct] = __builtin_amdgcn_mfma_f32_16x16x32_bf16(ah, bh[pg], acc[pg][ct], 0, 0, 0);
                    acc[pg][ct] = __builtin_amdgcn_mfma_f32_16x16x32_bf16(ah, bl[pg], acc[pg][ct], 0, 0, 0);
                    acc[pg][ct] = __builtin_amdgcn_mfma_f32_16x16x32_bf16(al, bh[pg], acc[pg][ct], 0, 0, 0);
                }
            }
        }
    }

    const int row = y0 + wave;
#pragma unroll
    for (int pg = 0; pg < 4; ++pg) {
        int px = x0 + pg * 16 + nl;
#pragma unroll
        for (int ct = 0; ct < NCT; ++ct) {
            int cb = ct * 16 + quad * 4;
            float r0 = fmaxf(acc[pg][ct][0] + bias[cb + 0], 0.f);
            float r1 = fmaxf(acc[pg][ct][1] + bias[cb + 1], 0.f);
            float r2 = fmaxf(acc[pg][ct][2] + bias[cb + 2], 0.f);
            float r3 = fmaxf(acc[pg][ct][3] + bias[cb + 3], 0.f);
            if (OUTMODE == 0) {
                size_t base = ((size_t)b * HWSZ + row * WW + px) * COUT + cb;
                ushort4 vh, vl;
                unsigned short h;
                h = f2bf(r0); vh.x = h; vl.x = f2bf(r0 - bf2f(h));
                h = f2bf(r1); vh.y = h; vl.y = f2bf(r1 - bf2f(h));
                h = f2bf(r2); vh.z = h; vl.z = f2bf(r2 - bf2f(h));
                h = f2bf(r3); vh.w = h; vl.w = f2bf(r3 - bf2f(h));
                *(ushort4*)(out_hi + base) = vh;
                *(ushort4*)(out_lo + base) = vl;
            } else {
                size_t sp = (size_t)row * WW + px;
                out_f32[((size_t)b * COUT + cb + 0) * HWSZ + sp] = r0;
                out_f32[((size_t)b * COUT + cb + 1) * HWSZ + sp] = r1;
                out_f32[((size_t)b * COUT + cb + 2) * HWSZ + sp] = r2;
                out_f32[((size_t)b * COUT + cb + 3) * HWSZ + sp] = r3;
            }
        }
    }
}

// ===========================================================================
// NUMERIC CHAIN — fp32
// ===========================================================================
__global__ __launch_bounds__(256) void lnpw_kernel(
    const float* __restrict__ x, const float* __restrict__ xb,
    const int* __restrict__ predp,
    const float* __restrict__ lnw, const float* __restrict__ lnb,
    const float* __restrict__ pww,
    float* __restrict__ qkvp)
{
    int p = blockIdx.x * 256 + threadIdx.x;
    if (p >= BB * HWSZ) return;
    int pr = __builtin_amdgcn_readfirstlane(*predp);
    const float* src = (pr == 0) ? x : xb;
    int b = p / HWSZ, n = p % HWSZ;
    const float* sp = src + (size_t)b * 32 * HWSZ + n;
    float v[32];
    float mean = 0.f;
#pragma unroll
    for (int c = 0; c < 32; ++c) { v[c] = sp[(size_t)c * HWSZ]; mean += v[c]; }
    mean *= (1.f / 32.f);
    float var = 0.f;
#pragma unroll
    for (int c = 0; c < 32; ++c) { float d = v[c] - mean; var += d * d; }
    var *= (1.f / 32.f);
    float rstd = rsqrtf(var + 1e-6f);
#pragma unroll
    for (int c = 0; c < 32; ++c)
        v[c] = (v[c] - mean) * rstd * lnw[c] + lnb[c];

    float acc[96];
#pragma unroll
    for (int co = 0; co < 96; ++co) acc[co] = 0.f;
    for (int ci = 0; ci < 32; ++ci) {
        float va = v[ci];
#pragma unroll
        for (int co = 0; co < 96; ++co)
            acc[co] = fmaf(pww[co * 32 + ci], va, acc[co]);
    }
    float* op = qkvp + (size_t)b * 96 * HWSZ + n;
#pragma unroll
    for (int co = 0; co < 96; ++co) op[(size_t)co * HWSZ] = acc[co];
}

// q/k depthwise-conv-on-the-fly + attention stats — LDS-staged (R5-proven:
// left the top-5 entirely; cooperative bulk staging beats per-thread ILP).
__global__ __launch_bounds__(256) void qkdwstats_kernel(
    const float* __restrict__ qkvp, const float* __restrict__ dww,
    float* __restrict__ stats)
{
    __shared__ float s_t[4][6][392];
    __shared__ float red[4][24];

    const int bh = blockIdx.y;
    const int b = bh >> 3, h = bh & 7;
    const float* qbase = qkvp + ((size_t)b * 96 + h * 4) * HWSZ;
    const float* kbase = qkvp + ((size_t)b * 96 + 32 + h * 4) * HWSZ;
    const float* wq = dww + (h * 4) * 9;
    const float* wk = dww + (32 + h * 4) * 9;

    const int tid  = threadIdx.x;
    const int w    = tid >> 6;      // wave -> output row y0+w
    const int lane = tid & 63;
    const int y0   = blockIdx.x * 4;

    // zero halo cells (cols 3 and 388 of every [ch][row]); persist both phases
    if (tid < 48) {
        int ch = tid / 12, rem = tid % 12;
        int r = rem >> 1, side = rem & 1;
        s_t[ch][r][side ? 388 : 3] = 0.f;
    }

    float s[16], qn[4], kn[4];
#pragma unroll
    for (int i = 0; i < 16; ++i) s[i] = 0.f;
#pragma unroll
    for (int i = 0; i < 4; ++i) { qn[i] = 0.f; kn[i] = 0.f; }

    // ---- phase 1: stage q channels ----
    {
#pragma unroll
        for (int i = 0; i < 9; ++i) {
            int idx = i * 256 + tid;            // [0, 2304)
            int ch  = idx / 576;
            int rem = idx - ch * 576;
            int r   = rem / 96;
            int g   = rem - r * 96;
            int gy  = y0 + r - 1;
            f32x4 v = {0.f, 0.f, 0.f, 0.f};
            if ((unsigned)gy < (unsigned)HH)
                v = *(const f32x4*)(qbase + (size_t)ch * HWSZ + (size_t)gy * WW + g * 4);
            *(f32x4*)&s_t[ch][r][g * 4 + 4] = v;   // 16B-aligned
        }
    }
    __syncthreads();

    // ---- compute q convs: q[ch][jj] for px col = jj*64+lane of row y0+w ----
    float q[4][6];
#pragma unroll
    for (int ch = 0; ch < 4; ++ch) {
        const float* w9 = wq + ch * 9;
#pragma unroll
        for (int jj = 0; jj < 6; ++jj) {
            int colL = jj * 64 + lane + 4;
            float acc = 0.f;
#pragma unroll
            for (int dy = 0; dy < 3; ++dy) {
                const float* rr = &s_t[ch][w + dy][0];
                acc = fmaf(rr[colL - 1], w9[dy * 3 + 0], acc);
                acc = fmaf(rr[colL    ], w9[dy * 3 + 1], acc);
                acc = fmaf(rr[colL + 1], w9[dy * 3 + 2], acc);
            }
            q[ch][jj] = acc;
            qn[ch] = fmaf(acc, acc, qn[ch]);
        }
    }
    __syncthreads();

    // ---- phase 2: stage k channels (reuse LDS) ----
    {
#pragma unroll
        for (int i = 0; i < 9; ++i) {
            int idx = i * 256 + tid;
            int ch  = idx / 576;
            int rem = idx - ch * 576;
            int r   = rem / 96;
            int g   = rem - r * 96;
            int gy  = y0 + r - 1;
            f32x4 v = {0.f, 0.f, 0.f, 0.f};
            if ((unsigned)gy < (unsigned)HH)
                v = *(const f32x4*)(kbase + (size_t)ch * HWSZ + (size_t)gy * WW + g * 4);
            *(f32x4*)&s_t[ch][r][g * 4 + 4] = v;
        }
    }
    __syncthreads();

    // ---- compute k convs, fuse stats ----
#pragma unroll
    for (int d = 0; d < 4; ++d) {
        const float* w9 = wk + d * 9;
#pragma unroll
        for (int jj = 0; jj < 6; ++jj) {
            int colL = jj * 64 + lane + 4;
            float kv = 0.f;
#pragma unroll
            for (int dy = 0; dy < 3; ++dy) {
                const float* rr = &s_t[d][w + dy][0];
                kv = fmaf(rr[colL - 1], w9[dy * 3 + 0], kv);
                kv = fmaf(rr[colL    ], w9[dy * 3 + 1], kv);
                kv = fmaf(rr[colL + 1], w9[dy * 3 + 2], kv);
            }
            kn[d] = fmaf(kv, kv, kn[d]);
#pragma unroll
            for (int c = 0; c < 4; ++c)
                s[c * 4 + d] = fmaf(q[c][jj], kv, s[c * 4 + d]);
        }
    }

    // ---- reduction: wave shuffle -> cross-wave LDS -> 1 atomic set/block ----
#pragma unroll
    for (int i = 0; i < 16; ++i) {
        float v = waveSum(s[i]);
        if (lane == 0) red[w][i] = v;
    }
#pragma unroll
    for (int i = 0; i < 4; ++i) {
        float v = waveSum(qn[i]);
        if (lane == 0) red[w][16 + i] = v;
        float u = waveSum(kn[i]);
        if (lane == 0) red[w][20 + i] = u;
    }
    __syncthreads();
    if (tid < 24) {
        float v = red[0][tid] + red[1][tid] + red[2][tid] + red[3][tid];
        atomicAdd(&stats[bh * 24 + tid], v);
    }
}

// v depthwise conv into q-channel slots. 8 px/thread (R1-proven form).
__global__ __launch_bounds__(256) void vdw_kernel(
    float* __restrict__ qkvp, const float* __restrict__ dww)
{
    int t = blockIdx.x * 256 + threadIdx.x;     // [0, 2359296)
    int bc = t / 18432;
    int g  = t - bc * 18432;
    int b = bc >> 5, c = bc & 31;
    int y  = g / 48;
    int xg = (g - y * 48) * 8;
    const float* ip = qkvp + ((size_t)b * 96 + 64 + c) * HWSZ;
    const float* wc = dww + (64 + c) * 9;
    float o[8];
    dwconv8(ip, wc, y, xg, o);
    float* op = qkvp + ((size_t)b * 96 + c) * HWSZ + (size_t)y * WW + xg;
    f32x4 v0 = {o[0], o[1], o[2], o[3]};
    f32x4 v1 = {o[4], o[5], o[6], o[7]};
    *(f32x4*)op = v0;
    *(f32x4*)(op + 4) = v1;
}

__global__ void attnmb_kernel(const float* __restrict__ stats,
                              const float* __restrict__ temp,
                              const float* __restrict__ projw,
                              float* __restrict__ Mb)
{
    __shared__ float attn_s[4][8][4][4];
    int t = threadIdx.x;
    if (t < 128) {
        int b = t >> 5;
        int h = (t >> 2) & 7;
        int c = t & 3;
        const float* st = stats + (b * 8 + h) * 24;
        float qn = fmaxf(sqrtf(st[16 + c]), 1e-12f);
        float tp = temp[h];
        float raw[4];
#pragma unroll
        for (int d = 0; d < 4; ++d) {
            float kn = fmaxf(sqrtf(st[20 + d]), 1e-12f);
            raw[d] = st[c * 4 + d] / (qn * kn) * tp;
        }
        float m = fmaxf(fmaxf(raw[0], raw[1]), fmaxf(raw[2], raw[3]));
        float e0 = expf(raw[0] - m), e1 = expf(raw[1] - m);
        float e2 = expf(raw[2] - m), e3 = expf(raw[3] - m);
        float inv = 1.f / (e0 + e1 + e2 + e3);
        attn_s[b][h][c][0] = e0 * inv;
        attn_s[b][h][c][1] = e1 * inv;
        attn_s[b][h][c][2] = e2 * inv;
        attn_s[b][h][c][3] = e3 * inv;
    }
    __syncthreads();
    for (int idx = t; idx < 4096; idx += 256) {
        int b = idx >> 10;
        int r = idx & 1023;
        int co = r >> 5;
        int j = r & 31;
        int h = j >> 2;
        int d = j & 3;
        float m = 0.f;
#pragma unroll
        for (int l = 0; l < 4; ++l)
            m = fmaf(projw[co * 32 + h * 4 + l], attn_s[b][h][l][d], m);
        Mb[idx] = m;
    }
}

__global__ __launch_bounds__(256) void e1_kernel(
    float* __restrict__ qkvp, const float* __restrict__ x,
    const float* __restrict__ xb, const int* __restrict__ predp,
    const float* __restrict__ Mb, const float* __restrict__ ff1w)
{
    int p = blockIdx.x * 256 + threadIdx.x;
    if (p >= BB * HWSZ) return;
    int pr = __builtin_amdgcn_readfirstlane(*predp);
    const float* src = (pr == 0) ? x : xb;
    int b = p / HWSZ, n = p % HWSZ;
    float* vp = qkvp + (size_t)b * 96 * HWSZ + n;
    const float* Mbb = Mb + b * 1024;
    float y[32];
#pragma unroll
    for (int c = 0; c < 32; ++c) y[c] = 0.f;
    for (int j = 0; j < 32; ++j) {
        float vj = vp[(size_t)j * HWSZ];
#pragma unroll
        for (int co = 0; co < 32; ++co)
            y[co] = fmaf(Mbb[co * 32 + j], vj, y[co]);
    }
    const float* xp = src + (size_t)b * 32 * HWSZ + n;
#pragma unroll
    for (int c = 0; c < 32; ++c) y[c] += xp[(size_t)c * HWSZ];
    for (int co = 0; co < 32; ++co) {
        float s = 0.f;
#pragma unroll
        for (int ci = 0; ci < 32; ++ci)
            s = fmaf(ff1w[co * 32 + ci], y[ci], s);
        vp[(size_t)co * HWSZ] = gelu_exact(s);
    }
}

// final depthwise conv + gelu. 8 px/thread (R1-proven form).
__global__ __launch_bounds__(256) void fdw_kernel(
    const float* __restrict__ z1, const float* __restrict__ w,
    float* __restrict__ out)
{
    int t = blockIdx.x * 256 + threadIdx.x;     // [0, 2359296)
    int bc = t / 18432;
    int g  = t - bc * 18432;
    int b = bc >> 5, c = bc & 31;
    int y  = g / 48;
    int xg = (g - y * 48) * 8;
    const float* ip = z1 + ((size_t)b * 96 + c) * HWSZ;
    const float* wc = w + c * 9;
    float o[8];
    dwconv8(ip, wc, y, xg, o);
#pragma unroll
    for (int j = 0; j < 8; ++j) o[j] = gelu_exact(o[j]);
    float* op = out + ((size_t)b * 32 + c) * HWSZ + (size_t)y * WW + xg;
    f32x4 v0 = {o[0], o[1], o[2], o[3]};
    f32x4 v1 = {o[4], o[5], o[6], o[7]};
    *(f32x4*)op = v0;
    *(f32x4*)(op + 4) = v1;
}

// ---------------------------------------------------------------------------
extern "C" void kernel_launch(void* const* d_in, const int* in_sizes, int n_in,
                              void* d_out, int out_size, void* d_ws, size_t ws_size,
                              hipStream_t stream)
{
    (void)in_sizes; (void)n_in; (void)out_size; (void)ws_size;
    const float* x      = (const float*)d_in[0];
    const float* ln_w   = (const float*)d_in[1];
    const float* ln_b   = (const float*)d_in[2];
    const float* temp   = (const float*)d_in[3];
    const float* pw_w   = (const float*)d_in[4];
    const float* dw_w   = (const float*)d_in[5];
    const float* proj_w = (const float*)d_in[6];
    const float* ff1_w  = (const float*)d_in[7];
    const float* ffdw_w = (const float*)d_in[8];
    const float* det_w1 = (const float*)d_in[9];
    const float* det_b1 = (const float*)d_in[10];
    const float* det_w2 = (const float*)d_in[11];
    const float* det_b2 = (const float*)d_in[12];
    const float* det_w3 = (const float*)d_in[13];
    const float* det_b3 = (const float*)d_in[14];
    const float* fc_w   = (const float*)d_in[15];
    const float* fc_b   = (const float*)d_in[16];
    const float* hvi_w1 = (const float*)d_in[17];
    const float* hvi_b1 = (const float*)d_in[18];
    const float* hvi_w2 = (const float*)d_in[19];
    const float* hvi_b2 = (const float*)d_in[20];
    const float* ycc_w1 = (const float*)d_in[21];
    const float* ycc_b1 = (const float*)d_in[22];
    const float* ycc_w2 = (const float*)d_in[23];
    const float* ycc_b2 = (const float*)d_in[24];

    float* ws     = (float*)d_ws;
    float* misc   = ws + OFF_MISC;
    float* A      = ws + OFF_A;
    // det phase
    unsigned short* x0bf  = (unsigned short*)A;
    unsigned short* f1bf  = (unsigned short*)(A + 2359296);
    unsigned short* f2bf  = (unsigned short*)(A + 7077888);
    unsigned short* d3out = (unsigned short*)(A + 16515072);
    unsigned short* w1p   = (unsigned short*)(A + 56423104);
    unsigned short* w2p   = (unsigned short*)(A + 56432320);
    unsigned short* w3p   = (unsigned short*)(A + 56469184);
    // branch phase
    unsigned short* xs_hi = (unsigned short*)A;
    unsigned short* xs_lo = (unsigned short*)(A + 9437184);
    unsigned short* t1_hi = (unsigned short*)(A + 18874368);
    unsigned short* t1_lo = (unsigned short*)(A + 37748736);
    unsigned short* bw    = (unsigned short*)(ws + OFF_BW);
    unsigned short* bw_h1h = bw;            unsigned short* bw_h1l = bw + 18432;
    unsigned short* bw_y1h = bw + 36864;    unsigned short* bw_y1l = bw + 55296;
    unsigned short* bw_h2h = bw + 73728;    unsigned short* bw_h2l = bw + 92160;
    unsigned short* bw_y2h = bw + 110592;   unsigned short* bw_y2l = bw + 129024;
    // qkv phase
    float* qkvp   = A;
    float* xb     = (float*)d_out;
    float* pooled = misc + MISC_POOLED;
    int*   pred   = (int*)(misc + MISC_PRED);
    float* stats  = misc + MISC_STATS;
    float* Mb     = misc + MISC_MB;
    float* out    = (float*)d_out;

    hipMemsetAsync(misc, 0, 2048 * sizeof(float), stream);

    dim3 blk(256);
    // ---- weight + input conversion ----
    wcvt_kernel<<<(18432 + 255) / 256, blk, 0, stream>>>(det_w1, w1p, 32, 18432);
    wcvt_kernel<<<(73728 + 255) / 256, blk, 0, stream>>>(det_w2, w2p, 64, 73728);
    wcvt_kernel<<<(294912 + 255) / 256, blk, 0, stream>>>(det_w3, w3p, 128, 294912);
    xcvt_kernel<<<576, blk, 0, stream>>>(x, x0bf);
    wsplit_kernel<<<72, blk, 0, stream>>>(hvi_w1, bw_h1h, bw_h1l, 32, 18432);
    wsplit_kernel<<<72, blk, 0, stream>>>(ycc_w1, bw_y1h, bw_y1l, 32, 18432);
    wsplit_kernel<<<72, blk, 0, stream>>>(hvi_w2, bw_h2h, bw_h2l, 64, 18432);
    wsplit_kernel<<<72, blk, 0, stream>>>(ycc_w2, bw_y2h, bw_y2l, 64, 18432);

    // ---- detector (batch 0 only; feeds argmax) ----
    mfma_conv2_kernel<32, 64>  <<<2304, blk, 0, stream>>>(x0bf, w1p, det_b1, f1bf);
    mfma_conv2_kernel<64, 128> <<<2304, blk, 0, stream>>>(f1bf, w2p, det_b2, f2bf);
    mfma_conv2_kernel<128, 256><<<2304, blk, 0, stream>>>(f2bf, w3p, det_b3, d3out);
    pool_kernel<<<64, blk, 0, stream>>>(d3out, pooled);
    fc_argmax_kernel<<<1, 256, 0, stream>>>(pooled, fc_w, fc_b, pred);

    // ---- gated color-space branch (bf16 hi/lo 3-MFMA; ~fp32 accuracy) ----
    xsplitb_kernel<<<2304, blk, 0, stream>>>(x, pred, xs_hi, xs_lo);
    bconv_kernel<32, 64, 0><<<dim3(576, BB), blk, 0, stream>>>(
        xs_hi, xs_lo, bw_h1h, bw_h1l, bw_y1h, bw_y1l, hvi_b1, ycc_b1, pred,
        t1_hi, t1_lo, nullptr);
    bconv_kernel<64, 32, 1><<<dim3(576, BB), blk, 0, stream>>>(
        t1_hi, t1_lo, bw_h2h, bw_h2l, bw_y2h, bw_y2l, hvi_b2, ycc_b2, pred,
        nullptr, nullptr, xb);

    // ---- fused LN + pw(1x1) -> qkvp ----
    lnpw_kernel<<<2304, blk, 0, stream>>>(x, xb, pred, ln_w, ln_b, pw_w, qkvp);

    // ---- q/k dw-on-the-fly + stats; v dw into q-channel slots ----
    qkdwstats_kernel<<<dim3(96, 32), blk, 0, stream>>>(qkvp, dw_w, stats);
    vdw_kernel<<<9216, blk, 0, stream>>>(qkvp, dw_w);
    attnmb_kernel<<<1, 256, 0, stream>>>(stats, temp, proj_w, Mb);

    // ---- epilogue ----
    e1_kernel<<<2304, blk, 0, stream>>>(qkvp, x, xb, pred, Mb, ff1_w);
    fdw_kernel<<<9216, blk, 0, stream>>>(qkvp, ffdw_w, out);
}